// Round 10
// baseline (373.879 us; speedup 1.0000x reference)
//
#include <hip/hip_runtime.h>

typedef __bf16 bf16;
typedef __bf16 bf16x4 __attribute__((ext_vector_type(4)));
typedef __bf16 bf16x8 __attribute__((ext_vector_type(8)));
typedef float f32x4 __attribute__((ext_vector_type(4)));

#define B_SZ 32768
#define T_CAT 26
#define V_SZ 100000
#define E_SZ 128

__device__ __forceinline__ void gload_lds16(const void* g, void* l) {
    __builtin_amdgcn_global_load_lds(
        (const __attribute__((address_space(1))) void*)g,
        (__attribute__((address_space(3))) void*)l, 16, 0, 0);
}

// compile-time triu(27, k=1) index LUT: p -> i*32+j  (351 entries)
struct TriuLut { unsigned short v[352]; };
static constexpr TriuLut makeTriu() {
    TriuLut l{};
    int p = 0;
    for (int i = 0; i < 27; ++i)
        for (int j = i + 1; j < 27; ++j) l.v[p++] = (unsigned short)(i * 32 + j);
    l.v[351] = 0;
    return l;
}
__device__ constexpr TriuLut kTriu = makeTriu();

// ---------------------------------------------------------------------------
// Merged weight convert with LDS transpose: W (K x N fp32) -> Wt (N x Kp bf16).
// ---------------------------------------------------------------------------
struct CJob { const float* W; bf16* Wt; int K, N, Kp, blk0, tk; };
struct CJobs { CJob j[7]; };

__global__ __launch_bounds__(256) void convw_all(CJobs js) {
    __shared__ bf16 tile[64][66];
    const int b = blockIdx.x;
    int ji = 0;
#pragma unroll
    for (int k = 1; k < 7; ++k)
        if (b >= js.j[k].blk0) ji = k;
    const CJob J = js.j[ji];
    const int local = b - J.blk0;
    const int tn = local / J.tk;
    const int tkk = local - tn * J.tk;

    const int t = threadIdx.x;
    const int lx = t & 63;
    const int gy = t >> 6;

#pragma unroll
    for (int kk = 0; kk < 16; ++kk) {
        const int k = tkk * 64 + kk * 4 + gy;
        const int n = tn * 64 + lx;
        const float v = (k < J.K) ? J.W[(long)k * J.N + n] : 0.0f;
        tile[lx][kk * 4 + gy] = (bf16)v;
    }
    __syncthreads();
#pragma unroll
    for (int nn = 0; nn < 16; ++nn) {
        const int nloc = nn * 4 + gy;
        const int n = tn * 64 + nloc;
        const int k = tkk * 64 + lx;
        J.Wt[(long)n * J.Kp + k] = tile[nloc][lx];
    }
}

// numerical (B x 13 fp32) -> xpad (B x 64 bf16)
__global__ __launch_bounds__(256) void make_xpad(const float* __restrict__ num,
                                                 bf16* __restrict__ xp) {
    const int idx = blockIdx.x * 256 + threadIdx.x;
    const int b = idx >> 6, c = idx & 63;
    xp[idx] = (bf16)((c < 13) ? num[(long)b * 13 + c] : 0.0f);
}

// ---------------------------------------------------------------------------
// 128x128 tile GEMM (m97 structure, 16x16x32 MFMA) — small/mid layers.
// ---------------------------------------------------------------------------
template <int RELU>
__global__ __launch_bounds__(256) void gemm_bt(const bf16* __restrict__ A,
                                               const bf16* __restrict__ Bt,
                                               const float* __restrict__ bias,
                                               bf16* __restrict__ C,
                                               int M, int N, int K) {
    __shared__ __align__(16) bf16 As[128 * 64];
    __shared__ __align__(16) bf16 Bs[128 * 64];
    const int t = threadIdx.x;
    const int lane = t & 63;
    const int w = t >> 6;
    const int wm = w >> 1, wn = w & 1;
    const long row0 = (long)blockIdx.y * 128;
    const long col0 = (long)blockIdx.x * 128;

    const int srow = t >> 3;
    const int scol = (t & 7) * 8;
    const bf16* Ag = A + (row0 + srow) * (long)K + scol;
    const bf16* Bg = Bt + (col0 + srow) * (long)K + scol;
    bf16* AsB = &As[w * 512];
    bf16* BsB = &Bs[w * 512];

    f32x4 acc[4][4] = {};

    for (int k0 = 0; k0 < K; k0 += 64) {
#pragma unroll
        for (int q = 0; q < 4; ++q) {
            gload_lds16(Ag + (long)q * 32 * K + k0, AsB + q * 2048);
            gload_lds16(Bg + (long)q * 32 * K + k0, BsB + q * 2048);
        }
        __syncthreads();
#pragma unroll
        for (int s = 0; s < 2; ++s) {
            bf16x8 af[4], bv[4];
#pragma unroll
            for (int i = 0; i < 4; ++i)
                af[i] = *(const bf16x8*)&As[(wm * 64 + i * 16 + (lane & 15)) * 64 +
                                            s * 32 + (lane >> 4) * 8];
#pragma unroll
            for (int j = 0; j < 4; ++j)
                bv[j] = *(const bf16x8*)&Bs[(wn * 64 + j * 16 + (lane & 15)) * 64 +
                                            s * 32 + (lane >> 4) * 8];
#pragma unroll
            for (int i = 0; i < 4; ++i)
#pragma unroll
                for (int j = 0; j < 4; ++j)
                    acc[i][j] = __builtin_amdgcn_mfma_f32_16x16x32_bf16(
                        af[i], bv[j], acc[i][j], 0, 0, 0);
        }
        __syncthreads();
    }

    const int r4 = (lane >> 4) * 4;
    const int cn = lane & 15;
#pragma unroll
    for (int j = 0; j < 4; ++j) {
        const long col = col0 + wn * 64 + j * 16 + cn;
        const float bj = bias[col];
#pragma unroll
        for (int i = 0; i < 4; ++i) {
#pragma unroll
            for (int r = 0; r < 4; ++r) {
                const long row = row0 + wm * 64 + i * 16 + r4 + r;
                float v = acc[i][j][r] + bj;
                if (RELU) v = v > 0.0f ? v : 0.0f;
                C[row * (long)N + col] = (bf16)v;
            }
        }
    }
}

// ---------------------------------------------------------------------------
// 256x256 GEMM, BK=64, 8-phase schedule (R5, correctness-proven) + both-sides
// XOR swizzle slot^=(row>>1)&3 (the missing T2 for T3 — R5 had 8-way bank
// conflicts on every ds_read_b128; this makes reads 2-way = free).
// Swizzle on the pre-swizzled GLOBAL source (gload_lds dest linear; 4-lane
// groups still cover one contiguous 64B row-half -> coalescing intact) and on
// the frag read (per-lane XOR term = (cm>>1)&3, constant across i/j).
// vmcnt(6) once per K-tile, never 0 in main loop. 8 waves (2x4).
// Requires M%256==0, N%256==0, K%128==0, K/64>=4, grid%8==0.
// ---------------------------------------------------------------------------
template <int RELU>
__global__ __launch_bounds__(512, 2) void gemm256(const bf16* __restrict__ A,
                                                  const bf16* __restrict__ Bt,
                                                  const float* __restrict__ bias,
                                                  bf16* __restrict__ C,
                                                  int M, int N, int K, int nbx) {
    // element layout: [buf(2)][mat(2): A,B][kh(2)][256 rows][32 k]
    __shared__ __align__(16) bf16 lds[65536];
    const int t = threadIdx.x;
    const int lane = t & 63;
    const int w = t >> 6;
    const int wm = w >> 2, wn = w & 3;

    const int nwg = gridDim.x;
    const int qch = nwg >> 3;
    const int swz = ((int)blockIdx.x & 7) * qch + ((int)blockIdx.x >> 3);
    const int bx = swz % nbx, by = swz / nbx;
    const long row0 = (long)by * 256;
    const long col0 = (long)bx * 256;

    const int NT = K >> 6;  // even, >= 4

    // staging: half-tile = [256 rows][32 k]; thread t -> row t>>2 (and +128),
    // LDS slot t&3; global slot pre-swizzled (involution, row+128 same term).
    const int srow = t >> 2;
    const int gsl = (t & 3) ^ ((srow >> 1) & 3);
    const bf16* Ag = A + (row0 + srow) * (long)K + gsl * 8;
    const bf16* Bg = Bt + (col0 + srow) * (long)K + gsl * 8;

#define STG(BUF, MAT, KH, KT)                                              \
    do {                                                                   \
        const bf16* _g = ((MAT) ? Bg : Ag) + (long)(KT)*64 + (KH)*32;      \
        bf16* _l = &lds[(BUF)*32768 + (MAT)*16384 + (KH)*8192 + w * 512];  \
        gload_lds16(_g, _l);                                               \
        gload_lds16(_g + 128 * (long)K, _l + 4096);                        \
    } while (0)

    // fragment bases; swizzled k-slot: kc ^ ((cm>>1)&3) — constant per lane
    // (rows differ by multiples of 16, so (row>>1)&3 == (cm>>1)&3 always).
    const int cm = lane & 15;
    const int kc = lane >> 4;
    const int kswz = (kc ^ ((cm >> 1) & 3)) * 8;
    const int abase = (wm * 128 + cm) * 32 + kswz;          // + i*512 + s*8192
    const int bbase = 16384 + (wn * 64 + cm) * 32 + kswz;   // + j*512 + s*8192

    bf16x8 bfr[4];
    f32x4 acc[8][4] = {};

#define PH(BUFB, S, IH, LOADB, STAGE, WAIT)                                   \
    do {                                                                      \
        if (LOADB) {                                                          \
            _Pragma("unroll") for (int j = 0; j < 4; ++j)                     \
                bfr[j] = *(const bf16x8*)&lds[(BUFB) + bbase + (S)*8192 + j*512]; \
        }                                                                     \
        bf16x8 af[4];                                                         \
        _Pragma("unroll") for (int i = 0; i < 4; ++i)                         \
            af[i] = *(const bf16x8*)&lds[(BUFB) + abase + (S)*8192 + ((IH)*4+i)*512]; \
        STAGE;                                                                \
        WAIT;                                                                 \
        asm volatile("" ::: "memory");                                       \
        __builtin_amdgcn_s_barrier();                                        \
        asm volatile("s_waitcnt lgkmcnt(0)" ::: "memory");                    \
        __builtin_amdgcn_s_setprio(1);                                       \
        _Pragma("unroll") for (int i = 0; i < 4; ++i)                         \
            _Pragma("unroll") for (int j = 0; j < 4; ++j)                     \
                acc[(IH)*4 + i][j] = __builtin_amdgcn_mfma_f32_16x16x32_bf16( \
                    af[i], bfr[j], acc[(IH)*4 + i][j], 0, 0, 0);              \
        __builtin_amdgcn_s_setprio(0);                                       \
        asm volatile("" ::: "memory");                                       \
        __builtin_amdgcn_s_barrier();                                        \
        asm volatile("" ::: "memory");                                       \
    } while (0)

#define TILE(BUFB, S1, S2, S3, S4, W4)          \
    PH(BUFB, 0, 0, 1, S1, ((void)0));           \
    PH(BUFB, 0, 1, 0, S2, ((void)0));           \
    PH(BUFB, 1, 0, 1, S3, ((void)0));           \
    PH(BUFB, 1, 1, 0, S4, W4)

#define VM6 asm volatile("s_waitcnt vmcnt(6)" ::: "memory")
#define VM0 asm volatile("s_waitcnt vmcnt(0)" ::: "memory")
#define NOP ((void)0)

    // prologue: tile0 full + tile1 (Bk0,Ak0,Bk1) = 14 loads
    STG(0, 1, 0, 0); STG(0, 0, 0, 0); STG(0, 1, 1, 0); STG(0, 0, 1, 0);
    STG(1, 1, 0, 1); STG(1, 0, 0, 1); STG(1, 1, 1, 1);
    VM6;  // tile 0 fully landed; 6 in flight
    __builtin_amdgcn_s_barrier();

    for (int tt = 0; tt + 3 < NT; tt += 2) {
        TILE(0,
             STG(1, 0, 1, tt + 1),   // Akh1(t+1) -> buf1
             STG(0, 1, 0, tt + 2),   // Bkh0(t+2) -> buf0 (freed end ph1)
             STG(0, 0, 0, tt + 2),   // Akh0(t+2)          (freed end ph2)
             STG(0, 1, 1, tt + 2),   // Bkh1(t+2)          (freed end ph3)
             VM6);
        TILE(32768,
             STG(0, 0, 1, tt + 2),
             STG(1, 1, 0, tt + 3),
             STG(1, 0, 0, tt + 3),
             STG(1, 1, 1, tt + 3),
             VM6);
    }
    // tail: tile NT-2 (buf0), tile NT-1 (buf1)
    TILE(0, STG(1, 0, 1, NT - 1), NOP, NOP, NOP, VM0);
    TILE(32768, NOP, NOP, NOP, NOP, NOP);

#undef STG
#undef PH
#undef TILE
#undef VM6
#undef VM0
#undef NOP

    // epilogue: D row = (lane>>4)*4 + reg, col = lane&15
    const int r4 = kc * 4;
#pragma unroll
    for (int j = 0; j < 4; ++j) {
        const long col = col0 + wn * 64 + j * 16 + cm;
        const float bj = bias[col];
#pragma unroll
        for (int i = 0; i < 8; ++i) {
#pragma unroll
            for (int r = 0; r < 4; ++r) {
                const long row = row0 + wm * 128 + i * 16 + r4 + r;
                float v = acc[i][j][r] + bj;
                if (RELU) v = v > 0.0f ? v : 0.0f;
                C[row * (long)N + col] = (bf16)v;
            }
        }
    }
}

// ---------------------------------------------------------------------------
// Fused embedding gather + pairwise interaction + top_in assembly.
// ---------------------------------------------------------------------------
__global__ __launch_bounds__(256) void interact_k(const float* __restrict__ emb,
                                                  const int* __restrict__ cat,
                                                  const bf16* __restrict__ bottom,
                                                  bf16* __restrict__ top_in) {
    __shared__ float gram[4][32 * 32];
    __shared__ __align__(16) bf16 rowbuf[4][512];
    const int t = threadIdx.x;
    const int lane = t & 63;
    const int w = t >> 6;
    const long s = (long)blockIdx.x * 4 + w;

    const int rl = lane & 15;
    const int kg = lane >> 4;

    bf16x8 f[2][4];
#pragma unroll
    for (int i = 0; i < 2; ++i) {
        const int r = i * 16 + rl;
        const float* rowp = nullptr;
        if (r >= 1 && r <= 26) {
            const int idx = cat[s * T_CAT + (r - 1)];
            rowp = emb + ((long)(r - 1) * V_SZ + idx) * E_SZ;
        }
#pragma unroll
        for (int ks = 0; ks < 4; ++ks) {
            const int c = ks * 32 + kg * 8;
            bf16x8 v = {};
            if (r == 0) {
                v = *(const bf16x8*)(bottom + s * 128 + c);
            } else if (r <= 26) {
                const float4 v0 = *(const float4*)(rowp + c);
                const float4 v1 = *(const float4*)(rowp + c + 4);
                v[0]=(bf16)v0.x; v[1]=(bf16)v0.y; v[2]=(bf16)v0.z; v[3]=(bf16)v0.w;
                v[4]=(bf16)v1.x; v[5]=(bf16)v1.y; v[6]=(bf16)v1.z; v[7]=(bf16)v1.w;
            }
            f[i][ks] = v;
        }
    }

    f32x4 a00 = {}, a01 = {}, a11 = {};
#pragma unroll
    for (int ks = 0; ks < 4; ++ks) {
        a00 = __builtin_amdgcn_mfma_f32_16x16x32_bf16(f[0][ks], f[0][ks], a00, 0, 0, 0);
        a01 = __builtin_amdgcn_mfma_f32_16x16x32_bf16(f[0][ks], f[1][ks], a01, 0, 0, 0);
        a11 = __builtin_amdgcn_mfma_f32_16x16x32_bf16(f[1][ks], f[1][ks], a11, 0, 0, 0);
    }

    const int r4 = kg * 4;
#pragma unroll
    for (int r = 0; r < 4; ++r) {
        gram[w][(r4 + r) * 32 + rl]           = a00[r];
        gram[w][(r4 + r) * 32 + 16 + rl]      = a01[r];
        gram[w][(16 + r4 + r) * 32 + 16 + rl] = a11[r];
    }
    asm volatile("s_waitcnt lgkmcnt(0)" ::: "memory");
    __builtin_amdgcn_sched_barrier(0);

    if (lane < 16)
        ((bf16x8*)&rowbuf[w][0])[lane] = ((const bf16x8*)(bottom + s * 128))[lane];
#pragma unroll
    for (int q = 0; q < 6; ++q) {
        const int p = q * 64 + lane;
        if (p < 351) rowbuf[w][128 + p] = (bf16)gram[w][kTriu.v[p]];
    }
    if (lane >= 31) rowbuf[w][448 + lane] = (bf16)0.0f;
    asm volatile("s_waitcnt lgkmcnt(0)" ::: "memory");
    __builtin_amdgcn_sched_barrier(0);

    *(bf16x8*)(top_in + s * 512 + lane * 8) = *(const bf16x8*)&rowbuf[w][lane * 8];
}

// ---------------------------------------------------------------------------
// Final layer GEMV.
// ---------------------------------------------------------------------------
__global__ __launch_bounds__(256) void gemv_final(const bf16* __restrict__ A,
                                                  const float* __restrict__ w4,
                                                  const float* __restrict__ b4,
                                                  float* __restrict__ out) {
    const int t = threadIdx.x;
    const int lane = t & 63;
    const int w = t >> 6;
    const long m = (long)blockIdx.x * 4 + w;
    const bf16x4 v = *(const bf16x4*)(A + m * 256 + lane * 4);
    const float4 wv = *(const float4*)(w4 + lane * 4);
    float sum = (float)v[0] * wv.x + (float)v[1] * wv.y + (float)v[2] * wv.z +
                (float)v[3] * wv.w;
#pragma unroll
    for (int off = 32; off > 0; off >>= 1) sum += __shfl_down(sum, off);
    if (lane == 0) out[m] = sum + b4[0];
}

// ---------------------------------------------------------------------------
extern "C" void kernel_launch(void* const* d_in, const int* in_sizes, int n_in,
                              void* d_out, int out_size, void* d_ws, size_t ws_size,
                              hipStream_t stream) {
    const float* numerical = (const float*)d_in[0];
    const int*   cat       = (const int*)d_in[1];
    const float* emb       = (const float*)d_in[2];
    const float* bw0 = (const float*)d_in[3];
    const float* bb0 = (const float*)d_in[4];
    const float* bw1 = (const float*)d_in[5];
    const float* bb1 = (const float*)d_in[6];
    const float* bw2 = (const float*)d_in[7];
    const float* bb2 = (const float*)d_in[8];
    const float* tw0 = (const float*)d_in[9];
    const float* tb0 = (const float*)d_in[10];
    const float* tw1 = (const float*)d_in[11];
    const float* tb1 = (const float*)d_in[12];
    const float* tw2 = (const float*)d_in[13];
    const float* tb2 = (const float*)d_in[14];
    const float* tw3 = (const float*)d_in[15];
    const float* tb3 = (const float*)d_in[16];
    const float* tw4 = (const float*)d_in[17];
    const float* tb4 = (const float*)d_in[18];
    float* out = (float*)d_out;

    char* ws = (char*)d_ws;
    size_t off = 0;
    auto alloc = [&](size_t bytes) {
        char* p = ws + off;
        off += (bytes + 255) & ~(size_t)255;
        return p;
    };
    bf16* wt0b = (bf16*)alloc((size_t)512 * 64 * 2);
    bf16* wt1b = (bf16*)alloc((size_t)256 * 512 * 2);
    bf16* wt2b = (bf16*)alloc((size_t)128 * 256 * 2);
    bf16* wt0t = (bf16*)alloc((size_t)1024 * 512 * 2);
    bf16* wt1t = (bf16*)alloc((size_t)1024 * 1024 * 2);
    bf16* wt2t = (bf16*)alloc((size_t)512 * 1024 * 2);
    bf16* wt3t = (bf16*)alloc((size_t)256 * 512 * 2);
    bf16* xpad = (bf16*)alloc((size_t)B_SZ * 64 * 2);
    bf16* h0   = (bf16*)alloc((size_t)B_SZ * 512 * 2);
    bf16* h1   = (bf16*)alloc((size_t)B_SZ * 256 * 2);
    bf16* bot  = (bf16*)alloc((size_t)B_SZ * 128 * 2);
    bf16* t0   = (bf16*)alloc((size_t)B_SZ * 1024 * 2);
    bf16* t1   = (bf16*)alloc((size_t)B_SZ * 1024 * 2);
    bf16* top_in = h0;
    bf16* t2 = t0;
    bf16* t3 = t1;

    CJobs js;
    js.j[0] = {bw0, wt0b, 16, 512, 64, 0, 1};
    js.j[1] = {bw1, wt1b, 512, 256, 512, 8, 8};
    js.j[2] = {bw2, wt2b, 256, 128, 256, 40, 4};
    js.j[3] = {tw0, wt0t, 480, 1024, 512, 48, 8};
    js.j[4] = {tw1, wt1t, 1024, 1024, 1024, 176, 16};
    js.j[5] = {tw2, wt2t, 1024, 512, 1024, 432, 16};
    js.j[6] = {tw3, wt3t, 512, 256, 512, 560, 8};
    convw_all<<<592, 256, 0, stream>>>(js);

    make_xpad<<<(B_SZ * 64) / 256, 256, 0, stream>>>(numerical, xpad);

    // bottom MLP
    gemm_bt<1><<<dim3(4, 256), 256, 0, stream>>>(xpad, wt0b, bb0, h0, B_SZ, 512, 64);
    gemm_bt<1><<<dim3(2, 256), 256, 0, stream>>>(h0, wt1b, bb1, h1, B_SZ, 256, 512);
    gemm_bt<1><<<dim3(1, 256), 256, 0, stream>>>(h1, wt2b, bb2, bot, B_SZ, 128, 256);

    interact_k<<<B_SZ / 4, 256, 0, stream>>>(emb, cat, bot, top_in);

    // top MLP: big 3 on the swizzled 8-phase 256^2 kernel
    gemm256<1><<<dim3(4 * 128), 512, 0, stream>>>(top_in, wt0t, tb0, t0, B_SZ, 1024, 512, 4);
    gemm256<1><<<dim3(4 * 128), 512, 0, stream>>>(t0, wt1t, tb1, t1, B_SZ, 1024, 1024, 4);
    gemm256<1><<<dim3(2 * 128), 512, 0, stream>>>(t1, wt2t, tb2, t2, B_SZ, 512, 1024, 2);
    gemm_bt<1><<<dim3(2, 256), 256, 0, stream>>>(t2, wt3t, tb3, t3, B_SZ, 256, 512);

    gemv_final<<<B_SZ / 4, 256, 0, stream>>>(t3, tw4, tb4, out);
}

// Round 11
// 335.351 us; speedup vs baseline: 1.1149x; 1.1149x over previous
//
#include <hip/hip_runtime.h>

typedef __bf16 bf16;
typedef __bf16 bf16x4 __attribute__((ext_vector_type(4)));
typedef __bf16 bf16x8 __attribute__((ext_vector_type(8)));
typedef float f32x4 __attribute__((ext_vector_type(4)));

#define B_SZ 32768
#define T_CAT 26
#define V_SZ 100000
#define E_SZ 128

__device__ __forceinline__ void gload_lds16(const void* g, void* l) {
    __builtin_amdgcn_global_load_lds(
        (const __attribute__((address_space(1))) void*)g,
        (__attribute__((address_space(3))) void*)l, 16, 0, 0);
}

// compile-time triu(27, k=1) index LUT: p -> i*32+j  (351 entries)
struct TriuLut { unsigned short v[352]; };
static constexpr TriuLut makeTriu() {
    TriuLut l{};
    int p = 0;
    for (int i = 0; i < 27; ++i)
        for (int j = i + 1; j < 27; ++j) l.v[p++] = (unsigned short)(i * 32 + j);
    l.v[351] = 0;
    return l;
}
__device__ constexpr TriuLut kTriu = makeTriu();

// ---------------------------------------------------------------------------
// Merged weight convert with LDS transpose: W (K x N fp32) -> Wt (N x Kp bf16).
// ---------------------------------------------------------------------------
struct CJob { const float* W; bf16* Wt; int K, N, Kp, blk0, tk; };
struct CJobs { CJob j[7]; };

__global__ __launch_bounds__(256) void convw_all(CJobs js) {
    __shared__ bf16 tile[64][66];
    const int b = blockIdx.x;
    int ji = 0;
#pragma unroll
    for (int k = 1; k < 7; ++k)
        if (b >= js.j[k].blk0) ji = k;
    const CJob J = js.j[ji];
    const int local = b - J.blk0;
    const int tn = local / J.tk;
    const int tkk = local - tn * J.tk;

    const int t = threadIdx.x;
    const int lx = t & 63;
    const int gy = t >> 6;

#pragma unroll
    for (int kk = 0; kk < 16; ++kk) {
        const int k = tkk * 64 + kk * 4 + gy;
        const int n = tn * 64 + lx;
        const float v = (k < J.K) ? J.W[(long)k * J.N + n] : 0.0f;
        tile[lx][kk * 4 + gy] = (bf16)v;
    }
    __syncthreads();
#pragma unroll
    for (int nn = 0; nn < 16; ++nn) {
        const int nloc = nn * 4 + gy;
        const int n = tn * 64 + nloc;
        const int k = tkk * 64 + lx;
        J.Wt[(long)n * J.Kp + k] = tile[nloc][lx];
    }
}

// numerical (B x 13 fp32) -> xpad (B x 64 bf16)
__global__ __launch_bounds__(256) void make_xpad(const float* __restrict__ num,
                                                 bf16* __restrict__ xp) {
    const int idx = blockIdx.x * 256 + threadIdx.x;
    const int b = idx >> 6, c = idx & 63;
    xp[idx] = (bf16)((c < 13) ? num[(long)b * 13 + c] : 0.0f);
}

// ---------------------------------------------------------------------------
// 128x128 tile GEMM (m97 structure, 16x16x32 MFMA) — small/mid layers.
// ~3 blocks/CU at 164 VGPR: cross-block overlap included (m114).
// ---------------------------------------------------------------------------
template <int RELU>
__global__ __launch_bounds__(256) void gemm_bt(const bf16* __restrict__ A,
                                               const bf16* __restrict__ Bt,
                                               const float* __restrict__ bias,
                                               bf16* __restrict__ C,
                                               int M, int N, int K) {
    __shared__ __align__(16) bf16 As[128 * 64];
    __shared__ __align__(16) bf16 Bs[128 * 64];
    const int t = threadIdx.x;
    const int lane = t & 63;
    const int w = t >> 6;
    const int wm = w >> 1, wn = w & 1;
    const long row0 = (long)blockIdx.y * 128;
    const long col0 = (long)blockIdx.x * 128;

    const int srow = t >> 3;
    const int scol = (t & 7) * 8;
    const bf16* Ag = A + (row0 + srow) * (long)K + scol;
    const bf16* Bg = Bt + (col0 + srow) * (long)K + scol;
    bf16* AsB = &As[w * 512];
    bf16* BsB = &Bs[w * 512];

    f32x4 acc[4][4] = {};

    for (int k0 = 0; k0 < K; k0 += 64) {
#pragma unroll
        for (int q = 0; q < 4; ++q) {
            gload_lds16(Ag + (long)q * 32 * K + k0, AsB + q * 2048);
            gload_lds16(Bg + (long)q * 32 * K + k0, BsB + q * 2048);
        }
        __syncthreads();
#pragma unroll
        for (int s = 0; s < 2; ++s) {
            bf16x8 af[4], bv[4];
#pragma unroll
            for (int i = 0; i < 4; ++i)
                af[i] = *(const bf16x8*)&As[(wm * 64 + i * 16 + (lane & 15)) * 64 +
                                            s * 32 + (lane >> 4) * 8];
#pragma unroll
            for (int j = 0; j < 4; ++j)
                bv[j] = *(const bf16x8*)&Bs[(wn * 64 + j * 16 + (lane & 15)) * 64 +
                                            s * 32 + (lane >> 4) * 8];
#pragma unroll
            for (int i = 0; i < 4; ++i)
#pragma unroll
                for (int j = 0; j < 4; ++j)
                    acc[i][j] = __builtin_amdgcn_mfma_f32_16x16x32_bf16(
                        af[i], bv[j], acc[i][j], 0, 0, 0);
        }
        __syncthreads();
    }

    const int r4 = (lane >> 4) * 4;
    const int cn = lane & 15;
#pragma unroll
    for (int j = 0; j < 4; ++j) {
        const long col = col0 + wn * 64 + j * 16 + cn;
        const float bj = bias[col];
#pragma unroll
        for (int i = 0; i < 4; ++i) {
#pragma unroll
            for (int r = 0; r < 4; ++r) {
                const long row = row0 + wm * 64 + i * 16 + r4 + r;
                float v = acc[i][j][r] + bj;
                if (RELU) v = v > 0.0f ? v : 0.0f;
                C[row * (long)N + col] = (bf16)v;
            }
        }
    }
}

// ---------------------------------------------------------------------------
// 256x128 tile GEMM, BK=64, 2-barrier loop, 16x16x32 MFMA, 8 waves (4m x 2n),
// wave tile 64x64 (R6 winner) — big top-MLP layers.
// __launch_bounds__(512,4) -> <=128 VGPR -> 2 blocks/CU; cross-block overlap
// hides barrier drain (m114). Both-sides XOR swizzle slot^=(row&7) (rule #21).
// Requires M%256==0, N%128==0, K%64==0, grid%8==0.
// ---------------------------------------------------------------------------
template <int RELU>
__global__ __launch_bounds__(512, 4) void gemm_bt2(const bf16* __restrict__ A,
                                                   const bf16* __restrict__ Bt,
                                                   const float* __restrict__ bias,
                                                   bf16* __restrict__ C,
                                                   int M, int N, int K, int nbx) {
    __shared__ __align__(16) bf16 As[256 * 64];  // 32 KB
    __shared__ __align__(16) bf16 Bs[128 * 64];  // 16 KB
    const int t = threadIdx.x;
    const int lane = t & 63;
    const int w = t >> 6;            // 0..7
    const int wm = w >> 1, wn = w & 1;

    const int nwg = gridDim.x;
    const int qch = nwg >> 3;
    const int swz = ((int)blockIdx.x & 7) * qch + ((int)blockIdx.x >> 3);
    const int bx = swz % nbx, by = swz / nbx;
    const long row0 = (long)by * 256;
    const long col0 = (long)bx * 128;

    const int srow = t >> 3;   // 0..63
    const int dslot = t & 7;
    const int gsl = dslot ^ (srow & 7);
    const bf16* Ag = A + (row0 + srow) * (long)K + gsl * 8;
    const bf16* Bg = Bt + (col0 + srow) * (long)K + gsl * 8;
    bf16* AsB = &As[w * 512];
    bf16* BsB = &Bs[w * 512];

    const int cm = lane & 15;
    const int kc = lane >> 4;

    f32x4 acc[4][4] = {};

    for (int k0 = 0; k0 < K; k0 += 64) {
#pragma unroll
        for (int q = 0; q < 4; ++q)
            gload_lds16(Ag + (long)q * 64 * K + k0, AsB + q * 4096);
#pragma unroll
        for (int q = 0; q < 2; ++q)
            gload_lds16(Bg + (long)q * 64 * K + k0, BsB + q * 4096);
        __syncthreads();
#pragma unroll
        for (int s = 0; s < 2; ++s) {
            bf16x8 af[4], bv[4];
#pragma unroll
            for (int i = 0; i < 4; ++i) {
                const int r = wm * 64 + i * 16 + cm;
                af[i] = *(const bf16x8*)&As[r * 64 + (((s * 4 + kc) ^ (r & 7)) * 8)];
            }
#pragma unroll
            for (int j = 0; j < 4; ++j) {
                const int r = wn * 64 + j * 16 + cm;
                bv[j] = *(const bf16x8*)&Bs[r * 64 + (((s * 4 + kc) ^ (r & 7)) * 8)];
            }
#pragma unroll
            for (int i = 0; i < 4; ++i)
#pragma unroll
                for (int j = 0; j < 4; ++j)
                    acc[i][j] = __builtin_amdgcn_mfma_f32_16x16x32_bf16(
                        af[i], bv[j], acc[i][j], 0, 0, 0);
        }
        __syncthreads();
    }

    const int r4 = kc * 4;
#pragma unroll
    for (int j = 0; j < 4; ++j) {
        const long col = col0 + wn * 64 + j * 16 + cm;
        const float bj = bias[col];
#pragma unroll
        for (int i = 0; i < 4; ++i) {
#pragma unroll
            for (int r = 0; r < 4; ++r) {
                const long row = row0 + wm * 64 + i * 16 + r4 + r;
                float v = acc[i][j][r] + bj;
                if (RELU) v = v > 0.0f ? v : 0.0f;
                C[row * (long)N + col] = (bf16)v;
            }
        }
    }
}

// ---------------------------------------------------------------------------
// Fused embedding gather + pairwise interaction + top_in assembly.
// ---------------------------------------------------------------------------
__global__ __launch_bounds__(256) void interact_k(const float* __restrict__ emb,
                                                  const int* __restrict__ cat,
                                                  const bf16* __restrict__ bottom,
                                                  bf16* __restrict__ top_in) {
    __shared__ float gram[4][32 * 32];
    __shared__ __align__(16) bf16 rowbuf[4][512];
    const int t = threadIdx.x;
    const int lane = t & 63;
    const int w = t >> 6;
    const long s = (long)blockIdx.x * 4 + w;

    const int rl = lane & 15;
    const int kg = lane >> 4;

    bf16x8 f[2][4];
#pragma unroll
    for (int i = 0; i < 2; ++i) {
        const int r = i * 16 + rl;
        const float* rowp = nullptr;
        if (r >= 1 && r <= 26) {
            const int idx = cat[s * T_CAT + (r - 1)];
            rowp = emb + ((long)(r - 1) * V_SZ + idx) * E_SZ;
        }
#pragma unroll
        for (int ks = 0; ks < 4; ++ks) {
            const int c = ks * 32 + kg * 8;
            bf16x8 v = {};
            if (r == 0) {
                v = *(const bf16x8*)(bottom + s * 128 + c);
            } else if (r <= 26) {
                const float4 v0 = *(const float4*)(rowp + c);
                const float4 v1 = *(const float4*)(rowp + c + 4);
                v[0]=(bf16)v0.x; v[1]=(bf16)v0.y; v[2]=(bf16)v0.z; v[3]=(bf16)v0.w;
                v[4]=(bf16)v1.x; v[5]=(bf16)v1.y; v[6]=(bf16)v1.z; v[7]=(bf16)v1.w;
            }
            f[i][ks] = v;
        }
    }

    f32x4 a00 = {}, a01 = {}, a11 = {};
#pragma unroll
    for (int ks = 0; ks < 4; ++ks) {
        a00 = __builtin_amdgcn_mfma_f32_16x16x32_bf16(f[0][ks], f[0][ks], a00, 0, 0, 0);
        a01 = __builtin_amdgcn_mfma_f32_16x16x32_bf16(f[0][ks], f[1][ks], a01, 0, 0, 0);
        a11 = __builtin_amdgcn_mfma_f32_16x16x32_bf16(f[1][ks], f[1][ks], a11, 0, 0, 0);
    }

    const int r4 = kg * 4;
#pragma unroll
    for (int r = 0; r < 4; ++r) {
        gram[w][(r4 + r) * 32 + rl]           = a00[r];
        gram[w][(r4 + r) * 32 + 16 + rl]      = a01[r];
        gram[w][(16 + r4 + r) * 32 + 16 + rl] = a11[r];
    }
    asm volatile("s_waitcnt lgkmcnt(0)" ::: "memory");
    __builtin_amdgcn_sched_barrier(0);

    if (lane < 16)
        ((bf16x8*)&rowbuf[w][0])[lane] = ((const bf16x8*)(bottom + s * 128))[lane];
#pragma unroll
    for (int q = 0; q < 6; ++q) {
        const int p = q * 64 + lane;
        if (p < 351) rowbuf[w][128 + p] = (bf16)gram[w][kTriu.v[p]];
    }
    if (lane >= 31) rowbuf[w][448 + lane] = (bf16)0.0f;
    asm volatile("s_waitcnt lgkmcnt(0)" ::: "memory");
    __builtin_amdgcn_sched_barrier(0);

    *(bf16x8*)(top_in + s * 512 + lane * 8) = *(const bf16x8*)&rowbuf[w][lane * 8];
}

// ---------------------------------------------------------------------------
// Final layer GEMV.
// ---------------------------------------------------------------------------
__global__ __launch_bounds__(256) void gemv_final(const bf16* __restrict__ A,
                                                  const float* __restrict__ w4,
                                                  const float* __restrict__ b4,
                                                  float* __restrict__ out) {
    const int t = threadIdx.x;
    const int lane = t & 63;
    const int w = t >> 6;
    const long m = (long)blockIdx.x * 4 + w;
    const bf16x4 v = *(const bf16x4*)(A + m * 256 + lane * 4);
    const float4 wv = *(const float4*)(w4 + lane * 4);
    float sum = (float)v[0] * wv.x + (float)v[1] * wv.y + (float)v[2] * wv.z +
                (float)v[3] * wv.w;
#pragma unroll
    for (int off = 32; off > 0; off >>= 1) sum += __shfl_down(sum, off);
    if (lane == 0) out[m] = sum + b4[0];
}

// ---------------------------------------------------------------------------
extern "C" void kernel_launch(void* const* d_in, const int* in_sizes, int n_in,
                              void* d_out, int out_size, void* d_ws, size_t ws_size,
                              hipStream_t stream) {
    const float* numerical = (const float*)d_in[0];
    const int*   cat       = (const int*)d_in[1];
    const float* emb       = (const float*)d_in[2];
    const float* bw0 = (const float*)d_in[3];
    const float* bb0 = (const float*)d_in[4];
    const float* bw1 = (const float*)d_in[5];
    const float* bb1 = (const float*)d_in[6];
    const float* bw2 = (const float*)d_in[7];
    const float* bb2 = (const float*)d_in[8];
    const float* tw0 = (const float*)d_in[9];
    const float* tb0 = (const float*)d_in[10];
    const float* tw1 = (const float*)d_in[11];
    const float* tb1 = (const float*)d_in[12];
    const float* tw2 = (const float*)d_in[13];
    const float* tb2 = (const float*)d_in[14];
    const float* tw3 = (const float*)d_in[15];
    const float* tb3 = (const float*)d_in[16];
    const float* tw4 = (const float*)d_in[17];
    const float* tb4 = (const float*)d_in[18];
    float* out = (float*)d_out;

    char* ws = (char*)d_ws;
    size_t off = 0;
    auto alloc = [&](size_t bytes) {
        char* p = ws + off;
        off += (bytes + 255) & ~(size_t)255;
        return p;
    };
    bf16* wt0b = (bf16*)alloc((size_t)512 * 64 * 2);
    bf16* wt1b = (bf16*)alloc((size_t)256 * 512 * 2);
    bf16* wt2b = (bf16*)alloc((size_t)128 * 256 * 2);
    bf16* wt0t = (bf16*)alloc((size_t)1024 * 512 * 2);
    bf16* wt1t = (bf16*)alloc((size_t)1024 * 1024 * 2);
    bf16* wt2t = (bf16*)alloc((size_t)512 * 1024 * 2);
    bf16* wt3t = (bf16*)alloc((size_t)256 * 512 * 2);
    bf16* xpad = (bf16*)alloc((size_t)B_SZ * 64 * 2);
    bf16* h0   = (bf16*)alloc((size_t)B_SZ * 512 * 2);
    bf16* h1   = (bf16*)alloc((size_t)B_SZ * 256 * 2);
    bf16* bot  = (bf16*)alloc((size_t)B_SZ * 128 * 2);
    bf16* t0   = (bf16*)alloc((size_t)B_SZ * 1024 * 2);
    bf16* t1   = (bf16*)alloc((size_t)B_SZ * 1024 * 2);
    bf16* top_in = h0;
    bf16* t2 = t0;
    bf16* t3 = t1;

    CJobs js;
    js.j[0] = {bw0, wt0b, 16, 512, 64, 0, 1};
    js.j[1] = {bw1, wt1b, 512, 256, 512, 8, 8};
    js.j[2] = {bw2, wt2b, 256, 128, 256, 40, 4};
    js.j[3] = {tw0, wt0t, 480, 1024, 512, 48, 8};
    js.j[4] = {tw1, wt1t, 1024, 1024, 1024, 176, 16};
    js.j[5] = {tw2, wt2t, 1024, 512, 1024, 432, 16};
    js.j[6] = {tw3, wt3t, 512, 256, 512, 560, 8};
    convw_all<<<592, 256, 0, stream>>>(js);

    make_xpad<<<(B_SZ * 64) / 256, 256, 0, stream>>>(numerical, xpad);

    // bottom MLP
    gemm_bt<1><<<dim3(4, 256), 256, 0, stream>>>(xpad, wt0b, bb0, h0, B_SZ, 512, 64);
    gemm_bt<1><<<dim3(2, 256), 256, 0, stream>>>(h0, wt1b, bb1, h1, B_SZ, 256, 512);
    gemm_bt<1><<<dim3(1, 256), 256, 0, stream>>>(h1, wt2b, bb2, bot, B_SZ, 128, 256);

    interact_k<<<B_SZ / 4, 256, 0, stream>>>(emb, cat, bot, top_in);

    // top MLP: big 3 on the R6-winning gemm_bt2; t3 on gemm_bt (512 blocks)
    gemm_bt2<1><<<dim3(1024), 512, 0, stream>>>(top_in, wt0t, tb0, t0, B_SZ, 1024, 512, 8);
    gemm_bt2<1><<<dim3(1024), 512, 0, stream>>>(t0, wt1t, tb1, t1, B_SZ, 1024, 1024, 8);
    gemm_bt2<1><<<dim3(512), 512, 0, stream>>>(t1, wt2t, tb2, t2, B_SZ, 512, 1024, 4);
    gemm_bt<1><<<dim3(2, 256), 256, 0, stream>>>(t2, wt3t, tb3, t3, B_SZ, 256, 512);

    gemv_final<<<B_SZ / 4, 256, 0, stream>>>(t3, tw4, tb4, out);
}

// Round 12
// 327.994 us; speedup vs baseline: 1.1399x; 1.0224x over previous
//
#include <hip/hip_runtime.h>

typedef __bf16 bf16;
typedef __bf16 bf16x4 __attribute__((ext_vector_type(4)));
typedef __bf16 bf16x8 __attribute__((ext_vector_type(8)));
typedef float f32x4 __attribute__((ext_vector_type(4)));

#define B_SZ 32768
#define T_CAT 26
#define V_SZ 100000
#define E_SZ 128

__device__ __forceinline__ void gload_lds16(const void* g, void* l) {
    __builtin_amdgcn_global_load_lds(
        (const __attribute__((address_space(1))) void*)g,
        (__attribute__((address_space(3))) void*)l, 16, 0, 0);
}

// compile-time triu(27, k=1) index LUT: p -> i*32+j  (351 entries)
struct TriuLut { unsigned short v[352]; };
static constexpr TriuLut makeTriu() {
    TriuLut l{};
    int p = 0;
    for (int i = 0; i < 27; ++i)
        for (int j = i + 1; j < 27; ++j) l.v[p++] = (unsigned short)(i * 32 + j);
    l.v[351] = 0;
    return l;
}
__device__ constexpr TriuLut kTriu = makeTriu();

// ---------------------------------------------------------------------------
// Merged weight convert with LDS transpose: W (K x N fp32) -> Wt (N x Kp bf16).
// ---------------------------------------------------------------------------
struct CJob { const float* W; bf16* Wt; int K, N, Kp, blk0, tk; };
struct CJobs { CJob j[7]; };

__global__ __launch_bounds__(256) void convw_all(CJobs js) {
    __shared__ bf16 tile[64][66];
    const int b = blockIdx.x;
    int ji = 0;
#pragma unroll
    for (int k = 1; k < 7; ++k)
        if (b >= js.j[k].blk0) ji = k;
    const CJob J = js.j[ji];
    const int local = b - J.blk0;
    const int tn = local / J.tk;
    const int tkk = local - tn * J.tk;

    const int t = threadIdx.x;
    const int lx = t & 63;
    const int gy = t >> 6;

#pragma unroll
    for (int kk = 0; kk < 16; ++kk) {
        const int k = tkk * 64 + kk * 4 + gy;
        const int n = tn * 64 + lx;
        const float v = (k < J.K) ? J.W[(long)k * J.N + n] : 0.0f;
        tile[lx][kk * 4 + gy] = (bf16)v;
    }
    __syncthreads();
#pragma unroll
    for (int nn = 0; nn < 16; ++nn) {
        const int nloc = nn * 4 + gy;
        const int n = tn * 64 + nloc;
        const int k = tkk * 64 + lx;
        J.Wt[(long)n * J.Kp + k] = tile[nloc][lx];
    }
}

// numerical (B x 13 fp32) -> xpad (B x 64 bf16)
__global__ __launch_bounds__(256) void make_xpad(const float* __restrict__ num,
                                                 bf16* __restrict__ xp) {
    const int idx = blockIdx.x * 256 + threadIdx.x;
    const int b = idx >> 6, c = idx & 63;
    xp[idx] = (bf16)((c < 13) ? num[(long)b * 13 + c] : 0.0f);
}

// out[m] = tb4[0]  (fp32 accumulator base for the fused final layer)
__global__ __launch_bounds__(256) void out_init(float* __restrict__ out,
                                                const float* __restrict__ b4) {
    out[blockIdx.x * 256 + threadIdx.x] = b4[0];
}

// ---------------------------------------------------------------------------
// 128x128 tile GEMM (m97 structure, 16x16x32 MFMA) — small/mid layers.
// ~3 blocks/CU at 164 VGPR: cross-block overlap included (m114).
// DOT=1: fused final layer — instead of storing C, fold relu(acc+bias)·w4[col]
// into per-row partials, butterfly-reduce across the 16 cn-lanes, and
// atomicAdd 16 row-partials from lane cn==0 (out pre-initialized to tb4).
// ---------------------------------------------------------------------------
template <int RELU, int DOT = 0>
__global__ __launch_bounds__(256) void gemm_bt(const bf16* __restrict__ A,
                                               const bf16* __restrict__ Bt,
                                               const float* __restrict__ bias,
                                               bf16* __restrict__ C,
                                               int M, int N, int K,
                                               const float* __restrict__ w4 = nullptr,
                                               float* __restrict__ out = nullptr) {
    __shared__ __align__(16) bf16 As[128 * 64];
    __shared__ __align__(16) bf16 Bs[128 * 64];
    const int t = threadIdx.x;
    const int lane = t & 63;
    const int w = t >> 6;
    const int wm = w >> 1, wn = w & 1;
    const long row0 = (long)blockIdx.y * 128;
    const long col0 = (long)blockIdx.x * 128;

    const int srow = t >> 3;
    const int scol = (t & 7) * 8;
    const bf16* Ag = A + (row0 + srow) * (long)K + scol;
    const bf16* Bg = Bt + (col0 + srow) * (long)K + scol;
    bf16* AsB = &As[w * 512];
    bf16* BsB = &Bs[w * 512];

    f32x4 acc[4][4] = {};

    for (int k0 = 0; k0 < K; k0 += 64) {
#pragma unroll
        for (int q = 0; q < 4; ++q) {
            gload_lds16(Ag + (long)q * 32 * K + k0, AsB + q * 2048);
            gload_lds16(Bg + (long)q * 32 * K + k0, BsB + q * 2048);
        }
        __syncthreads();
#pragma unroll
        for (int s = 0; s < 2; ++s) {
            bf16x8 af[4], bv[4];
#pragma unroll
            for (int i = 0; i < 4; ++i)
                af[i] = *(const bf16x8*)&As[(wm * 64 + i * 16 + (lane & 15)) * 64 +
                                            s * 32 + (lane >> 4) * 8];
#pragma unroll
            for (int j = 0; j < 4; ++j)
                bv[j] = *(const bf16x8*)&Bs[(wn * 64 + j * 16 + (lane & 15)) * 64 +
                                            s * 32 + (lane >> 4) * 8];
#pragma unroll
            for (int i = 0; i < 4; ++i)
#pragma unroll
                for (int j = 0; j < 4; ++j)
                    acc[i][j] = __builtin_amdgcn_mfma_f32_16x16x32_bf16(
                        af[i], bv[j], acc[i][j], 0, 0, 0);
        }
        __syncthreads();
    }

    const int r4 = (lane >> 4) * 4;
    const int cn = lane & 15;

    if (DOT) {
        float part[16] = {};
#pragma unroll
        for (int j = 0; j < 4; ++j) {
            const long col = col0 + wn * 64 + j * 16 + cn;
            const float bj = bias[col];
            const float wj = w4[col];
#pragma unroll
            for (int i = 0; i < 4; ++i)
#pragma unroll
                for (int r = 0; r < 4; ++r) {
                    float v = acc[i][j][r] + bj;
                    v = v > 0.0f ? v : 0.0f;
                    part[i * 4 + r] += v * wj;
                }
        }
#pragma unroll
        for (int k = 0; k < 16; ++k)
#pragma unroll
            for (int m = 1; m < 16; m <<= 1)
                part[k] += __shfl_xor(part[k], m);
        if (cn == 0) {
#pragma unroll
            for (int i = 0; i < 4; ++i)
#pragma unroll
                for (int r = 0; r < 4; ++r) {
                    const long row = row0 + wm * 64 + i * 16 + r4 + r;
                    atomicAdd(&out[row], part[i * 4 + r]);
                }
        }
        return;
    }

#pragma unroll
    for (int j = 0; j < 4; ++j) {
        const long col = col0 + wn * 64 + j * 16 + cn;
        const float bj = bias[col];
#pragma unroll
        for (int i = 0; i < 4; ++i) {
#pragma unroll
            for (int r = 0; r < 4; ++r) {
                const long row = row0 + wm * 64 + i * 16 + r4 + r;
                float v = acc[i][j][r] + bj;
                if (RELU) v = v > 0.0f ? v : 0.0f;
                C[row * (long)N + col] = (bf16)v;
            }
        }
    }
}

// ---------------------------------------------------------------------------
// 256x128 tile GEMM, BK=64, 2-barrier loop, 16x16x32 MFMA, 8 waves (4m x 2n),
// wave tile 64x64 (R6 winner) — big top-MLP layers.
// __launch_bounds__(512,4) -> <=128 VGPR -> 2 blocks/CU; cross-block overlap
// hides barrier drain (m114). Both-sides XOR swizzle slot^=(row&7) (rule #21).
// Requires M%256==0, N%128==0, K%64==0, grid%8==0.
// ---------------------------------------------------------------------------
template <int RELU>
__global__ __launch_bounds__(512, 4) void gemm_bt2(const bf16* __restrict__ A,
                                                   const bf16* __restrict__ Bt,
                                                   const float* __restrict__ bias,
                                                   bf16* __restrict__ C,
                                                   int M, int N, int K, int nbx) {
    __shared__ __align__(16) bf16 As[256 * 64];  // 32 KB
    __shared__ __align__(16) bf16 Bs[128 * 64];  // 16 KB
    const int t = threadIdx.x;
    const int lane = t & 63;
    const int w = t >> 6;            // 0..7
    const int wm = w >> 1, wn = w & 1;

    const int nwg = gridDim.x;
    const int qch = nwg >> 3;
    const int swz = ((int)blockIdx.x & 7) * qch + ((int)blockIdx.x >> 3);
    const int bx = swz % nbx, by = swz / nbx;
    const long row0 = (long)by * 256;
    const long col0 = (long)bx * 128;

    const int srow = t >> 3;   // 0..63
    const int dslot = t & 7;
    const int gsl = dslot ^ (srow & 7);
    const bf16* Ag = A + (row0 + srow) * (long)K + gsl * 8;
    const bf16* Bg = Bt + (col0 + srow) * (long)K + gsl * 8;
    bf16* AsB = &As[w * 512];
    bf16* BsB = &Bs[w * 512];

    const int cm = lane & 15;
    const int kc = lane >> 4;

    f32x4 acc[4][4] = {};

    for (int k0 = 0; k0 < K; k0 += 64) {
#pragma unroll
        for (int q = 0; q < 4; ++q)
            gload_lds16(Ag + (long)q * 64 * K + k0, AsB + q * 4096);
#pragma unroll
        for (int q = 0; q < 2; ++q)
            gload_lds16(Bg + (long)q * 64 * K + k0, BsB + q * 4096);
        __syncthreads();
#pragma unroll
        for (int s = 0; s < 2; ++s) {
            bf16x8 af[4], bv[4];
#pragma unroll
            for (int i = 0; i < 4; ++i) {
                const int r = wm * 64 + i * 16 + cm;
                af[i] = *(const bf16x8*)&As[r * 64 + (((s * 4 + kc) ^ (r & 7)) * 8)];
            }
#pragma unroll
            for (int j = 0; j < 4; ++j) {
                const int r = wn * 64 + j * 16 + cm;
                bv[j] = *(const bf16x8*)&Bs[r * 64 + (((s * 4 + kc) ^ (r & 7)) * 8)];
            }
#pragma unroll
            for (int i = 0; i < 4; ++i)
#pragma unroll
                for (int j = 0; j < 4; ++j)
                    acc[i][j] = __builtin_amdgcn_mfma_f32_16x16x32_bf16(
                        af[i], bv[j], acc[i][j], 0, 0, 0);
        }
        __syncthreads();
    }

    const int r4 = kc * 4;
#pragma unroll
    for (int j = 0; j < 4; ++j) {
        const long col = col0 + wn * 64 + j * 16 + cm;
        const float bj = bias[col];
#pragma unroll
        for (int i = 0; i < 4; ++i) {
#pragma unroll
            for (int r = 0; r < 4; ++r) {
                const long row = row0 + wm * 64 + i * 16 + r4 + r;
                float v = acc[i][j][r] + bj;
                if (RELU) v = v > 0.0f ? v : 0.0f;
                C[row * (long)N + col] = (bf16)v;
            }
        }
    }
}

// ---------------------------------------------------------------------------
// Fused embedding gather + pairwise interaction + top_in assembly.
// ---------------------------------------------------------------------------
__global__ __launch_bounds__(256) void interact_k(const float* __restrict__ emb,
                                                  const int* __restrict__ cat,
                                                  const bf16* __restrict__ bottom,
                                                  bf16* __restrict__ top_in) {
    __shared__ float gram[4][32 * 32];
    __shared__ __align__(16) bf16 rowbuf[4][512];
    const int t = threadIdx.x;
    const int lane = t & 63;
    const int w = t >> 6;
    const long s = (long)blockIdx.x * 4 + w;

    const int rl = lane & 15;
    const int kg = lane >> 4;

    bf16x8 f[2][4];
#pragma unroll
    for (int i = 0; i < 2; ++i) {
        const int r = i * 16 + rl;
        const float* rowp = nullptr;
        if (r >= 1 && r <= 26) {
            const int idx = cat[s * T_CAT + (r - 1)];
            rowp = emb + ((long)(r - 1) * V_SZ + idx) * E_SZ;
        }
#pragma unroll
        for (int ks = 0; ks < 4; ++ks) {
            const int c = ks * 32 + kg * 8;
            bf16x8 v = {};
            if (r == 0) {
                v = *(const bf16x8*)(bottom + s * 128 + c);
            } else if (r <= 26) {
                const float4 v0 = *(const float4*)(rowp + c);
                const float4 v1 = *(const float4*)(rowp + c + 4);
                v[0]=(bf16)v0.x; v[1]=(bf16)v0.y; v[2]=(bf16)v0.z; v[3]=(bf16)v0.w;
                v[4]=(bf16)v1.x; v[5]=(bf16)v1.y; v[6]=(bf16)v1.z; v[7]=(bf16)v1.w;
            }
            f[i][ks] = v;
        }
    }

    f32x4 a00 = {}, a01 = {}, a11 = {};
#pragma unroll
    for (int ks = 0; ks < 4; ++ks) {
        a00 = __builtin_amdgcn_mfma_f32_16x16x32_bf16(f[0][ks], f[0][ks], a00, 0, 0, 0);
        a01 = __builtin_amdgcn_mfma_f32_16x16x32_bf16(f[0][ks], f[1][ks], a01, 0, 0, 0);
        a11 = __builtin_amdgcn_mfma_f32_16x16x32_bf16(f[1][ks], f[1][ks], a11, 0, 0, 0);
    }

    const int r4 = kg * 4;
#pragma unroll
    for (int r = 0; r < 4; ++r) {
        gram[w][(r4 + r) * 32 + rl]           = a00[r];
        gram[w][(r4 + r) * 32 + 16 + rl]      = a01[r];
        gram[w][(16 + r4 + r) * 32 + 16 + rl] = a11[r];
    }
    asm volatile("s_waitcnt lgkmcnt(0)" ::: "memory");
    __builtin_amdgcn_sched_barrier(0);

    if (lane < 16)
        ((bf16x8*)&rowbuf[w][0])[lane] = ((const bf16x8*)(bottom + s * 128))[lane];
#pragma unroll
    for (int q = 0; q < 6; ++q) {
        const int p = q * 64 + lane;
        if (p < 351) rowbuf[w][128 + p] = (bf16)gram[w][kTriu.v[p]];
    }
    if (lane >= 31) rowbuf[w][448 + lane] = (bf16)0.0f;
    asm volatile("s_waitcnt lgkmcnt(0)" ::: "memory");
    __builtin_amdgcn_sched_barrier(0);

    *(bf16x8*)(top_in + s * 512 + lane * 8) = *(const bf16x8*)&rowbuf[w][lane * 8];
}

// ---------------------------------------------------------------------------
extern "C" void kernel_launch(void* const* d_in, const int* in_sizes, int n_in,
                              void* d_out, int out_size, void* d_ws, size_t ws_size,
                              hipStream_t stream) {
    const float* numerical = (const float*)d_in[0];
    const int*   cat       = (const int*)d_in[1];
    const float* emb       = (const float*)d_in[2];
    const float* bw0 = (const float*)d_in[3];
    const float* bb0 = (const float*)d_in[4];
    const float* bw1 = (const float*)d_in[5];
    const float* bb1 = (const float*)d_in[6];
    const float* bw2 = (const float*)d_in[7];
    const float* bb2 = (const float*)d_in[8];
    const float* tw0 = (const float*)d_in[9];
    const float* tb0 = (const float*)d_in[10];
    const float* tw1 = (const float*)d_in[11];
    const float* tb1 = (const float*)d_in[12];
    const float* tw2 = (const float*)d_in[13];
    const float* tb2 = (const float*)d_in[14];
    const float* tw3 = (const float*)d_in[15];
    const float* tb3 = (const float*)d_in[16];
    const float* tw4 = (const float*)d_in[17];
    const float* tb4 = (const float*)d_in[18];
    float* out = (float*)d_out;

    char* ws = (char*)d_ws;
    size_t off = 0;
    auto alloc = [&](size_t bytes) {
        char* p = ws + off;
        off += (bytes + 255) & ~(size_t)255;
        return p;
    };
    bf16* wt0b = (bf16*)alloc((size_t)512 * 64 * 2);
    bf16* wt1b = (bf16*)alloc((size_t)256 * 512 * 2);
    bf16* wt2b = (bf16*)alloc((size_t)128 * 256 * 2);
    bf16* wt0t = (bf16*)alloc((size_t)1024 * 512 * 2);
    bf16* wt1t = (bf16*)alloc((size_t)1024 * 1024 * 2);
    bf16* wt2t = (bf16*)alloc((size_t)512 * 1024 * 2);
    bf16* wt3t = (bf16*)alloc((size_t)256 * 512 * 2);
    bf16* xpad = (bf16*)alloc((size_t)B_SZ * 64 * 2);
    bf16* h0   = (bf16*)alloc((size_t)B_SZ * 512 * 2);
    bf16* h1   = (bf16*)alloc((size_t)B_SZ * 256 * 2);
    bf16* bot  = (bf16*)alloc((size_t)B_SZ * 128 * 2);
    bf16* t0   = (bf16*)alloc((size_t)B_SZ * 1024 * 2);
    bf16* t1   = (bf16*)alloc((size_t)B_SZ * 1024 * 2);
    bf16* top_in = h0;
    bf16* t2 = t0;

    CJobs js;
    js.j[0] = {bw0, wt0b, 16, 512, 64, 0, 1};
    js.j[1] = {bw1, wt1b, 512, 256, 512, 8, 8};
    js.j[2] = {bw2, wt2b, 256, 128, 256, 40, 4};
    js.j[3] = {tw0, wt0t, 480, 1024, 512, 48, 8};
    js.j[4] = {tw1, wt1t, 1024, 1024, 1024, 176, 16};
    js.j[5] = {tw2, wt2t, 1024, 512, 1024, 432, 16};
    js.j[6] = {tw3, wt3t, 512, 256, 512, 560, 8};
    convw_all<<<592, 256, 0, stream>>>(js);

    make_xpad<<<(B_SZ * 64) / 256, 256, 0, stream>>>(numerical, xpad);
    out_init<<<B_SZ / 256, 256, 0, stream>>>(out, tb4);

    // bottom MLP
    gemm_bt<1><<<dim3(4, 256), 256, 0, stream>>>(xpad, wt0b, bb0, h0, B_SZ, 512, 64);
    gemm_bt<1><<<dim3(2, 256), 256, 0, stream>>>(h0, wt1b, bb1, h1, B_SZ, 256, 512);
    gemm_bt<1><<<dim3(1, 256), 256, 0, stream>>>(h1, wt2b, bb2, bot, B_SZ, 128, 256);

    interact_k<<<B_SZ / 4, 256, 0, stream>>>(emb, cat, bot, top_in);

    // top MLP: big 3 on gemm_bt2; final two layers fused (t3 GEMM + dot w4)
    gemm_bt2<1><<<dim3(1024), 512, 0, stream>>>(top_in, wt0t, tb0, t0, B_SZ, 1024, 512, 8);
    gemm_bt2<1><<<dim3(1024), 512, 0, stream>>>(t0, wt1t, tb1, t1, B_SZ, 1024, 1024, 8);
    gemm_bt2<1><<<dim3(512), 512, 0, stream>>>(t1, wt2t, tb2, t2, B_SZ, 512, 1024, 4);
    gemm_bt<1, 1><<<dim3(2, 256), 256, 0, stream>>>(t2, wt3t, tb3, nullptr,
                                                    B_SZ, 256, 512, tw4, out);
}

// Round 13
// 321.283 us; speedup vs baseline: 1.1637x; 1.0209x over previous
//
#include <hip/hip_runtime.h>

typedef __bf16 bf16;
typedef __bf16 bf16x4 __attribute__((ext_vector_type(4)));
typedef __bf16 bf16x8 __attribute__((ext_vector_type(8)));
typedef float f32x4 __attribute__((ext_vector_type(4)));

#define B_SZ 32768
#define T_CAT 26
#define V_SZ 100000
#define E_SZ 128

__device__ __forceinline__ void gload_lds16(const void* g, void* l) {
    __builtin_amdgcn_global_load_lds(
        (const __attribute__((address_space(1))) void*)g,
        (__attribute__((address_space(3))) void*)l, 16, 0, 0);
}

// compile-time triu(27, k=1) index LUT: p -> i*32+j  (351 entries)
struct TriuLut { unsigned short v[352]; };
static constexpr TriuLut makeTriu() {
    TriuLut l{};
    int p = 0;
    for (int i = 0; i < 27; ++i)
        for (int j = i + 1; j < 27; ++j) l.v[p++] = (unsigned short)(i * 32 + j);
    l.v[351] = 0;
    return l;
}
__device__ constexpr TriuLut kTriu = makeTriu();

// ---------------------------------------------------------------------------
// Fused prep kernel: [0,592) weight convert+transpose; [592,1616) xpad
// (vectorized bf16x8 stores); [1616,1744) out init to tb4.
// ---------------------------------------------------------------------------
struct CJob { const float* W; bf16* Wt; int K, N, Kp, blk0, tk; };
struct CJobs { CJob j[7]; };

#define XPAD_BLK0 592
#define OINIT_BLK0 1616
#define PREP_BLKS 1744

__global__ __launch_bounds__(256) void prep(CJobs js,
                                            const float* __restrict__ num,
                                            bf16* __restrict__ xp,
                                            float* __restrict__ out,
                                            const float* __restrict__ b4) {
    const int b = blockIdx.x;
    const int t = threadIdx.x;

    if (b >= OINIT_BLK0) {
        out[(b - OINIT_BLK0) * 256 + t] = b4[0];
        return;
    }
    if (b >= XPAD_BLK0) {
        // xpad: each thread writes one 8-elem bf16 chunk (16 B)
        const int e8 = (b - XPAD_BLK0) * 256 + t;  // 262144 chunks
        const int row = e8 >> 3;
        const int chunk = e8 & 7;
        bf16x8 v = {};
        if (chunk < 2) {
#pragma unroll
            for (int k = 0; k < 8; ++k) {
                const int col = chunk * 8 + k;
                v[k] = (bf16)((col < 13) ? num[(long)row * 13 + col] : 0.0f);
            }
        }
        *(bf16x8*)(xp + (long)row * 64 + chunk * 8) = v;
        return;
    }

    __shared__ bf16 tile[64][66];
    int ji = 0;
#pragma unroll
    for (int k = 1; k < 7; ++k)
        if (b >= js.j[k].blk0) ji = k;
    const CJob J = js.j[ji];
    const int local = b - J.blk0;
    const int tn = local / J.tk;
    const int tkk = local - tn * J.tk;

    const int lx = t & 63;
    const int gy = t >> 6;

#pragma unroll
    for (int kk = 0; kk < 16; ++kk) {
        const int k = tkk * 64 + kk * 4 + gy;
        const int n = tn * 64 + lx;
        const float v = (k < J.K) ? J.W[(long)k * J.N + n] : 0.0f;
        tile[lx][kk * 4 + gy] = (bf16)v;
    }
    __syncthreads();
#pragma unroll
    for (int nn = 0; nn < 16; ++nn) {
        const int nloc = nn * 4 + gy;
        const int n = tn * 64 + nloc;
        const int k = tkk * 64 + lx;
        J.Wt[(long)n * J.Kp + k] = tile[nloc][lx];
    }
}

// ---------------------------------------------------------------------------
// 128x128 tile GEMM (m97 structure, 16x16x32 MFMA) — small/mid layers.
// ~3 blocks/CU at 164 VGPR: cross-block overlap included (m114).
// DOT=1: fused final layer — fold relu(acc+bias)·w4[col] into per-row
// partials, butterfly-reduce across the 16 cn-lanes, atomicAdd from cn==0
// (out pre-initialized to tb4).
// ---------------------------------------------------------------------------
template <int RELU, int DOT = 0>
__global__ __launch_bounds__(256) void gemm_bt(const bf16* __restrict__ A,
                                               const bf16* __restrict__ Bt,
                                               const float* __restrict__ bias,
                                               bf16* __restrict__ C,
                                               int M, int N, int K,
                                               const float* __restrict__ w4 = nullptr,
                                               float* __restrict__ out = nullptr) {
    __shared__ __align__(16) bf16 As[128 * 64];
    __shared__ __align__(16) bf16 Bs[128 * 64];
    const int t = threadIdx.x;
    const int lane = t & 63;
    const int w = t >> 6;
    const int wm = w >> 1, wn = w & 1;
    const long row0 = (long)blockIdx.y * 128;
    const long col0 = (long)blockIdx.x * 128;

    const int srow = t >> 3;
    const int scol = (t & 7) * 8;
    const bf16* Ag = A + (row0 + srow) * (long)K + scol;
    const bf16* Bg = Bt + (col0 + srow) * (long)K + scol;
    bf16* AsB = &As[w * 512];
    bf16* BsB = &Bs[w * 512];

    f32x4 acc[4][4] = {};

    for (int k0 = 0; k0 < K; k0 += 64) {
#pragma unroll
        for (int q = 0; q < 4; ++q) {
            gload_lds16(Ag + (long)q * 32 * K + k0, AsB + q * 2048);
            gload_lds16(Bg + (long)q * 32 * K + k0, BsB + q * 2048);
        }
        __syncthreads();
#pragma unroll
        for (int s = 0; s < 2; ++s) {
            bf16x8 af[4], bv[4];
#pragma unroll
            for (int i = 0; i < 4; ++i)
                af[i] = *(const bf16x8*)&As[(wm * 64 + i * 16 + (lane & 15)) * 64 +
                                            s * 32 + (lane >> 4) * 8];
#pragma unroll
            for (int j = 0; j < 4; ++j)
                bv[j] = *(const bf16x8*)&Bs[(wn * 64 + j * 16 + (lane & 15)) * 64 +
                                            s * 32 + (lane >> 4) * 8];
#pragma unroll
            for (int i = 0; i < 4; ++i)
#pragma unroll
                for (int j = 0; j < 4; ++j)
                    acc[i][j] = __builtin_amdgcn_mfma_f32_16x16x32_bf16(
                        af[i], bv[j], acc[i][j], 0, 0, 0);
        }
        __syncthreads();
    }

    const int r4 = (lane >> 4) * 4;
    const int cn = lane & 15;

    if (DOT) {
        float part[16] = {};
#pragma unroll
        for (int j = 0; j < 4; ++j) {
            const long col = col0 + wn * 64 + j * 16 + cn;
            const float bj = bias[col];
            const float wj = w4[col];
#pragma unroll
            for (int i = 0; i < 4; ++i)
#pragma unroll
                for (int r = 0; r < 4; ++r) {
                    float v = acc[i][j][r] + bj;
                    v = v > 0.0f ? v : 0.0f;
                    part[i * 4 + r] += v * wj;
                }
        }
#pragma unroll
        for (int k = 0; k < 16; ++k)
#pragma unroll
            for (int m = 1; m < 16; m <<= 1)
                part[k] += __shfl_xor(part[k], m);
        if (cn == 0) {
#pragma unroll
            for (int i = 0; i < 4; ++i)
#pragma unroll
                for (int r = 0; r < 4; ++r) {
                    const long row = row0 + wm * 64 + i * 16 + r4 + r;
                    atomicAdd(&out[row], part[i * 4 + r]);
                }
        }
        return;
    }

#pragma unroll
    for (int j = 0; j < 4; ++j) {
        const long col = col0 + wn * 64 + j * 16 + cn;
        const float bj = bias[col];
#pragma unroll
        for (int i = 0; i < 4; ++i) {
#pragma unroll
            for (int r = 0; r < 4; ++r) {
                const long row = row0 + wm * 64 + i * 16 + r4 + r;
                float v = acc[i][j][r] + bj;
                if (RELU) v = v > 0.0f ? v : 0.0f;
                C[row * (long)N + col] = (bf16)v;
            }
        }
    }
}

// ---------------------------------------------------------------------------
// 256x128 tile GEMM, BK=64, 2-barrier loop, 16x16x32 MFMA, 8 waves (4m x 2n),
// wave tile 64x64 (R6 winner) — big top-MLP layers.
// __launch_bounds__(512,4) -> <=128 VGPR -> 2 blocks/CU; cross-block overlap
// hides barrier drain (m114). Both-sides XOR swizzle slot^=(row&7) (rule #21).
// Requires M%256==0, N%128==0, K%64==0, grid%8==0.
// ---------------------------------------------------------------------------
template <int RELU>
__global__ __launch_bounds__(512, 4) void gemm_bt2(const bf16* __restrict__ A,
                                                   const bf16* __restrict__ Bt,
                                                   const float* __restrict__ bias,
                                                   bf16* __restrict__ C,
                                                   int M, int N, int K, int nbx) {
    __shared__ __align__(16) bf16 As[256 * 64];  // 32 KB
    __shared__ __align__(16) bf16 Bs[128 * 64];  // 16 KB
    const int t = threadIdx.x;
    const int lane = t & 63;
    const int w = t >> 6;            // 0..7
    const int wm = w >> 1, wn = w & 1;

    const int nwg = gridDim.x;
    const int qch = nwg >> 3;
    const int swz = ((int)blockIdx.x & 7) * qch + ((int)blockIdx.x >> 3);
    const int bx = swz % nbx, by = swz / nbx;
    const long row0 = (long)by * 256;
    const long col0 = (long)bx * 128;

    const int srow = t >> 3;   // 0..63
    const int dslot = t & 7;
    const int gsl = dslot ^ (srow & 7);
    const bf16* Ag = A + (row0 + srow) * (long)K + gsl * 8;
    const bf16* Bg = Bt + (col0 + srow) * (long)K + gsl * 8;
    bf16* AsB = &As[w * 512];
    bf16* BsB = &Bs[w * 512];

    const int cm = lane & 15;
    const int kc = lane >> 4;

    f32x4 acc[4][4] = {};

    for (int k0 = 0; k0 < K; k0 += 64) {
#pragma unroll
        for (int q = 0; q < 4; ++q)
            gload_lds16(Ag + (long)q * 64 * K + k0, AsB + q * 4096);
#pragma unroll
        for (int q = 0; q < 2; ++q)
            gload_lds16(Bg + (long)q * 64 * K + k0, BsB + q * 4096);
        __syncthreads();
#pragma unroll
        for (int s = 0; s < 2; ++s) {
            bf16x8 af[4], bv[4];
#pragma unroll
            for (int i = 0; i < 4; ++i) {
                const int r = wm * 64 + i * 16 + cm;
                af[i] = *(const bf16x8*)&As[r * 64 + (((s * 4 + kc) ^ (r & 7)) * 8)];
            }
#pragma unroll
            for (int j = 0; j < 4; ++j) {
                const int r = wn * 64 + j * 16 + cm;
                bv[j] = *(const bf16x8*)&Bs[r * 64 + (((s * 4 + kc) ^ (r & 7)) * 8)];
            }
#pragma unroll
            for (int i = 0; i < 4; ++i)
#pragma unroll
                for (int j = 0; j < 4; ++j)
                    acc[i][j] = __builtin_amdgcn_mfma_f32_16x16x32_bf16(
                        af[i], bv[j], acc[i][j], 0, 0, 0);
        }
        __syncthreads();
    }

    const int r4 = kc * 4;
#pragma unroll
    for (int j = 0; j < 4; ++j) {
        const long col = col0 + wn * 64 + j * 16 + cm;
        const float bj = bias[col];
#pragma unroll
        for (int i = 0; i < 4; ++i) {
#pragma unroll
            for (int r = 0; r < 4; ++r) {
                const long row = row0 + wm * 64 + i * 16 + r4 + r;
                float v = acc[i][j][r] + bj;
                if (RELU) v = v > 0.0f ? v : 0.0f;
                C[row * (long)N + col] = (bf16)v;
            }
        }
    }
}

// ---------------------------------------------------------------------------
// Fused embedding gather + pairwise interaction + top_in assembly.
// ---------------------------------------------------------------------------
__global__ __launch_bounds__(256) void interact_k(const float* __restrict__ emb,
                                                  const int* __restrict__ cat,
                                                  const bf16* __restrict__ bottom,
                                                  bf16* __restrict__ top_in) {
    __shared__ float gram[4][32 * 32];
    __shared__ __align__(16) bf16 rowbuf[4][512];
    const int t = threadIdx.x;
    const int lane = t & 63;
    const int w = t >> 6;
    const long s = (long)blockIdx.x * 4 + w;

    const int rl = lane & 15;
    const int kg = lane >> 4;

    bf16x8 f[2][4];
#pragma unroll
    for (int i = 0; i < 2; ++i) {
        const int r = i * 16 + rl;
        const float* rowp = nullptr;
        if (r >= 1 && r <= 26) {
            const int idx = cat[s * T_CAT + (r - 1)];
            rowp = emb + ((long)(r - 1) * V_SZ + idx) * E_SZ;
        }
#pragma unroll
        for (int ks = 0; ks < 4; ++ks) {
            const int c = ks * 32 + kg * 8;
            bf16x8 v = {};
            if (r == 0) {
                v = *(const bf16x8*)(bottom + s * 128 + c);
            } else if (r <= 26) {
                const float4 v0 = *(const float4*)(rowp + c);
                const float4 v1 = *(const float4*)(rowp + c + 4);
                v[0]=(bf16)v0.x; v[1]=(bf16)v0.y; v[2]=(bf16)v0.z; v[3]=(bf16)v0.w;
                v[4]=(bf16)v1.x; v[5]=(bf16)v1.y; v[6]=(bf16)v1.z; v[7]=(bf16)v1.w;
            }
            f[i][ks] = v;
        }
    }

    f32x4 a00 = {}, a01 = {}, a11 = {};
#pragma unroll
    for (int ks = 0; ks < 4; ++ks) {
        a00 = __builtin_amdgcn_mfma_f32_16x16x32_bf16(f[0][ks], f[0][ks], a00, 0, 0, 0);
        a01 = __builtin_amdgcn_mfma_f32_16x16x32_bf16(f[0][ks], f[1][ks], a01, 0, 0, 0);
        a11 = __builtin_amdgcn_mfma_f32_16x16x32_bf16(f[1][ks], f[1][ks], a11, 0, 0, 0);
    }

    const int r4 = kg * 4;
#pragma unroll
    for (int r = 0; r < 4; ++r) {
        gram[w][(r4 + r) * 32 + rl]           = a00[r];
        gram[w][(r4 + r) * 32 + 16 + rl]      = a01[r];
        gram[w][(16 + r4 + r) * 32 + 16 + rl] = a11[r];
    }
    asm volatile("s_waitcnt lgkmcnt(0)" ::: "memory");
    __builtin_amdgcn_sched_barrier(0);

    if (lane < 16)
        ((bf16x8*)&rowbuf[w][0])[lane] = ((const bf16x8*)(bottom + s * 128))[lane];
#pragma unroll
    for (int q = 0; q < 6; ++q) {
        const int p = q * 64 + lane;
        if (p < 351) rowbuf[w][128 + p] = (bf16)gram[w][kTriu.v[p]];
    }
    if (lane >= 31) rowbuf[w][448 + lane] = (bf16)0.0f;
    asm volatile("s_waitcnt lgkmcnt(0)" ::: "memory");
    __builtin_amdgcn_sched_barrier(0);

    *(bf16x8*)(top_in + s * 512 + lane * 8) = *(const bf16x8*)&rowbuf[w][lane * 8];
}

// ---------------------------------------------------------------------------
extern "C" void kernel_launch(void* const* d_in, const int* in_sizes, int n_in,
                              void* d_out, int out_size, void* d_ws, size_t ws_size,
                              hipStream_t stream) {
    const float* numerical = (const float*)d_in[0];
    const int*   cat       = (const int*)d_in[1];
    const float* emb       = (const float*)d_in[2];
    const float* bw0 = (const float*)d_in[3];
    const float* bb0 = (const float*)d_in[4];
    const float* bw1 = (const float*)d_in[5];
    const float* bb1 = (const float*)d_in[6];
    const float* bw2 = (const float*)d_in[7];
    const float* bb2 = (const float*)d_in[8];
    const float* tw0 = (const float*)d_in[9];
    const float* tb0 = (const float*)d_in[10];
    const float* tw1 = (const float*)d_in[11];
    const float* tb1 = (const float*)d_in[12];
    const float* tw2 = (const float*)d_in[13];
    const float* tb2 = (const float*)d_in[14];
    const float* tw3 = (const float*)d_in[15];
    const float* tb3 = (const float*)d_in[16];
    const float* tw4 = (const float*)d_in[17];
    const float* tb4 = (const float*)d_in[18];
    float* out = (float*)d_out;

    char* ws = (char*)d_ws;
    size_t off = 0;
    auto alloc = [&](size_t bytes) {
        char* p = ws + off;
        off += (bytes + 255) & ~(size_t)255;
        return p;
    };
    bf16* wt0b = (bf16*)alloc((size_t)512 * 64 * 2);
    bf16* wt1b = (bf16*)alloc((size_t)256 * 512 * 2);
    bf16* wt2b = (bf16*)alloc((size_t)128 * 256 * 2);
    bf16* wt0t = (bf16*)alloc((size_t)1024 * 512 * 2);
    bf16* wt1t = (bf16*)alloc((size_t)1024 * 1024 * 2);
    bf16* wt2t = (bf16*)alloc((size_t)512 * 1024 * 2);
    bf16* wt3t = (bf16*)alloc((size_t)256 * 512 * 2);
    bf16* xpad = (bf16*)alloc((size_t)B_SZ * 64 * 2);
    bf16* h0   = (bf16*)alloc((size_t)B_SZ * 512 * 2);
    bf16* h1   = (bf16*)alloc((size_t)B_SZ * 256 * 2);
    bf16* bot  = (bf16*)alloc((size_t)B_SZ * 128 * 2);
    bf16* t0   = (bf16*)alloc((size_t)B_SZ * 1024 * 2);
    bf16* t1   = (bf16*)alloc((size_t)B_SZ * 1024 * 2);
    bf16* top_in = h0;
    bf16* t2 = t0;

    CJobs js;
    js.j[0] = {bw0, wt0b, 16, 512, 64, 0, 1};
    js.j[1] = {bw1, wt1b, 512, 256, 512, 8, 8};
    js.j[2] = {bw2, wt2b, 256, 128, 256, 40, 4};
    js.j[3] = {tw0, wt0t, 480, 1024, 512, 48, 8};
    js.j[4] = {tw1, wt1t, 1024, 1024, 1024, 176, 16};
    js.j[5] = {tw2, wt2t, 1024, 512, 1024, 432, 16};
    js.j[6] = {tw3, wt3t, 512, 256, 512, 560, 8};

    prep<<<PREP_BLKS, 256, 0, stream>>>(js, numerical, xpad, out, tb4);

    // bottom MLP
    gemm_bt<1><<<dim3(4, 256), 256, 0, stream>>>(xpad, wt0b, bb0, h0, B_SZ, 512, 64);
    gemm_bt<1><<<dim3(2, 256), 256, 0, stream>>>(h0, wt1b, bb1, h1, B_SZ, 256, 512);
    gemm_bt<1><<<dim3(1, 256), 256, 0, stream>>>(h1, wt2b, bb2, bot, B_SZ, 128, 256);

    interact_k<<<B_SZ / 4, 256, 0, stream>>>(emb, cat, bot, top_in);

    // top MLP: big 3 on gemm_bt2; final two layers fused (t3 GEMM + dot w4)
    gemm_bt2<1><<<dim3(1024), 512, 0, stream>>>(top_in, wt0t, tb0, t0, B_SZ, 1024, 512, 8);
    gemm_bt2<1><<<dim3(1024), 512, 0, stream>>>(t0, wt1t, tb1, t1, B_SZ, 1024, 1024, 8);
    gemm_bt2<1><<<dim3(512), 512, 0, stream>>>(t1, wt2t, tb2, t2, B_SZ, 512, 1024, 4);
    gemm_bt<1, 1><<<dim3(2, 256), 256, 0, stream>>>(t2, wt3t, tb3, nullptr,
                                                    B_SZ, 256, 512, tw4, out);
}

// Round 14
// 319.565 us; speedup vs baseline: 1.1700x; 1.0054x over previous
//
#include <hip/hip_runtime.h>

typedef __bf16 bf16;
typedef __bf16 bf16x4 __attribute__((ext_vector_type(4)));
typedef __bf16 bf16x8 __attribute__((ext_vector_type(8)));
typedef float f32x4 __attribute__((ext_vector_type(4)));

#define B_SZ 32768
#define T_CAT 26
#define V_SZ 100000
#define E_SZ 128

__device__ __forceinline__ void gload_lds16(const void* g, void* l) {
    __builtin_amdgcn_global_load_lds(
        (const __attribute__((address_space(1))) void*)g,
        (__attribute__((address_space(3))) void*)l, 16, 0, 0);
}

// compile-time triu(27, k=1) index LUT: p -> i*32+j  (351 entries)
struct TriuLut { unsigned short v[352]; };
static constexpr TriuLut makeTriu() {
    TriuLut l{};
    int p = 0;
    for (int i = 0; i < 27; ++i)
        for (int j = i + 1; j < 27; ++j) l.v[p++] = (unsigned short)(i * 32 + j);
    l.v[351] = 0;
    return l;
}
__device__ constexpr TriuLut kTriu = makeTriu();

// ---------------------------------------------------------------------------
// Fused prep kernel: [0,592) weight convert+transpose; [592,1616) xpad
// (vectorized bf16x8 stores); [1616,1744) out init to tb4.
// ---------------------------------------------------------------------------
struct CJob { const float* W; bf16* Wt; int K, N, Kp, blk0, tk; };
struct CJobs { CJob j[7]; };

#define XPAD_BLK0 592
#define OINIT_BLK0 1616
#define PREP_BLKS 1744

__global__ __launch_bounds__(256) void prep(CJobs js,
                                            const float* __restrict__ num,
                                            bf16* __restrict__ xp,
                                            float* __restrict__ out,
                                            const float* __restrict__ b4) {
    const int b = blockIdx.x;
    const int t = threadIdx.x;

    if (b >= OINIT_BLK0) {
        out[(b - OINIT_BLK0) * 256 + t] = b4[0];
        return;
    }
    if (b >= XPAD_BLK0) {
        const int e8 = (b - XPAD_BLK0) * 256 + t;  // 262144 chunks
        const int row = e8 >> 3;
        const int chunk = e8 & 7;
        bf16x8 v = {};
        if (chunk < 2) {
#pragma unroll
            for (int k = 0; k < 8; ++k) {
                const int col = chunk * 8 + k;
                v[k] = (bf16)((col < 13) ? num[(long)row * 13 + col] : 0.0f);
            }
        }
        *(bf16x8*)(xp + (long)row * 64 + chunk * 8) = v;
        return;
    }

    __shared__ bf16 tile[64][66];
    int ji = 0;
#pragma unroll
    for (int k = 1; k < 7; ++k)
        if (b >= js.j[k].blk0) ji = k;
    const CJob J = js.j[ji];
    const int local = b - J.blk0;
    const int tn = local / J.tk;
    const int tkk = local - tn * J.tk;

    const int lx = t & 63;
    const int gy = t >> 6;

#pragma unroll
    for (int kk = 0; kk < 16; ++kk) {
        const int k = tkk * 64 + kk * 4 + gy;
        const int n = tn * 64 + lx;
        const float v = (k < J.K) ? J.W[(long)k * J.N + n] : 0.0f;
        tile[lx][kk * 4 + gy] = (bf16)v;
    }
    __syncthreads();
#pragma unroll
    for (int nn = 0; nn < 16; ++nn) {
        const int nloc = nn * 4 + gy;
        const int n = tn * 64 + nloc;
        const int k = tkk * 64 + lx;
        J.Wt[(long)n * J.Kp + k] = tile[nloc][lx];
    }
}

// ---------------------------------------------------------------------------
// 128x128 tile GEMM (m97 structure, 16x16x32 MFMA) — small/mid layers.
// ~3 blocks/CU at 164 VGPR: cross-block overlap included (m114).
// DOT=1: fused final layer — fold relu(acc+bias)·w4[col] into per-row
// partials, butterfly-reduce across the 16 cn-lanes, atomicAdd from cn==0
// (out pre-initialized to tb4).
// ---------------------------------------------------------------------------
template <int RELU, int DOT = 0>
__global__ __launch_bounds__(256) void gemm_bt(const bf16* __restrict__ A,
                                               const bf16* __restrict__ Bt,
                                               const float* __restrict__ bias,
                                               bf16* __restrict__ C,
                                               int M, int N, int K,
                                               const float* __restrict__ w4 = nullptr,
                                               float* __restrict__ out = nullptr) {
    __shared__ __align__(16) bf16 As[128 * 64];
    __shared__ __align__(16) bf16 Bs[128 * 64];
    const int t = threadIdx.x;
    const int lane = t & 63;
    const int w = t >> 6;
    const int wm = w >> 1, wn = w & 1;
    const long row0 = (long)blockIdx.y * 128;
    const long col0 = (long)blockIdx.x * 128;

    const int srow = t >> 3;
    const int scol = (t & 7) * 8;
    const bf16* Ag = A + (row0 + srow) * (long)K + scol;
    const bf16* Bg = Bt + (col0 + srow) * (long)K + scol;
    bf16* AsB = &As[w * 512];
    bf16* BsB = &Bs[w * 512];

    f32x4 acc[4][4] = {};

    for (int k0 = 0; k0 < K; k0 += 64) {
#pragma unroll
        for (int q = 0; q < 4; ++q) {
            gload_lds16(Ag + (long)q * 32 * K + k0, AsB + q * 2048);
            gload_lds16(Bg + (long)q * 32 * K + k0, BsB + q * 2048);
        }
        __syncthreads();
#pragma unroll
        for (int s = 0; s < 2; ++s) {
            bf16x8 af[4], bv[4];
#pragma unroll
            for (int i = 0; i < 4; ++i)
                af[i] = *(const bf16x8*)&As[(wm * 64 + i * 16 + (lane & 15)) * 64 +
                                            s * 32 + (lane >> 4) * 8];
#pragma unroll
            for (int j = 0; j < 4; ++j)
                bv[j] = *(const bf16x8*)&Bs[(wn * 64 + j * 16 + (lane & 15)) * 64 +
                                            s * 32 + (lane >> 4) * 8];
#pragma unroll
            for (int i = 0; i < 4; ++i)
#pragma unroll
                for (int j = 0; j < 4; ++j)
                    acc[i][j] = __builtin_amdgcn_mfma_f32_16x16x32_bf16(
                        af[i], bv[j], acc[i][j], 0, 0, 0);
        }
        __syncthreads();
    }

    const int r4 = (lane >> 4) * 4;
    const int cn = lane & 15;

    if (DOT) {
        float part[16] = {};
#pragma unroll
        for (int j = 0; j < 4; ++j) {
            const long col = col0 + wn * 64 + j * 16 + cn;
            const float bj = bias[col];
            const float wj = w4[col];
#pragma unroll
            for (int i = 0; i < 4; ++i)
#pragma unroll
                for (int r = 0; r < 4; ++r) {
                    float v = acc[i][j][r] + bj;
                    v = v > 0.0f ? v : 0.0f;
                    part[i * 4 + r] += v * wj;
                }
        }
#pragma unroll
        for (int k = 0; k < 16; ++k)
#pragma unroll
            for (int m = 1; m < 16; m <<= 1)
                part[k] += __shfl_xor(part[k], m);
        if (cn == 0) {
#pragma unroll
            for (int i = 0; i < 4; ++i)
#pragma unroll
                for (int r = 0; r < 4; ++r) {
                    const long row = row0 + wm * 64 + i * 16 + r4 + r;
                    atomicAdd(&out[row], part[i * 4 + r]);
                }
        }
        return;
    }

#pragma unroll
    for (int j = 0; j < 4; ++j) {
        const long col = col0 + wn * 64 + j * 16 + cn;
        const float bj = bias[col];
#pragma unroll
        for (int i = 0; i < 4; ++i) {
#pragma unroll
            for (int r = 0; r < 4; ++r) {
                const long row = row0 + wm * 64 + i * 16 + r4 + r;
                float v = acc[i][j][r] + bj;
                if (RELU) v = v > 0.0f ? v : 0.0f;
                C[row * (long)N + col] = (bf16)v;
            }
        }
    }
}

// ---------------------------------------------------------------------------
// 256x128 tile GEMM, BK=64, 2-barrier loop, 16x16x32 MFMA, 8 waves (4m x 2n),
// wave tile 64x64 (R6 winner) — big top-MLP layers.
// __launch_bounds__(512,4) -> <=128 VGPR -> 2 blocks/CU; cross-block overlap
// hides barrier drain (m114). Both-sides XOR swizzle slot^=(row&7) (rule #21).
// NEW (R14): LDS-staged coalesced epilogue — C tile staged through the freed
// 48 KB As/Bs buffer in two 128-row halves (row stride 132 breaks kc-group
// bank aliasing; scalar ds_writes 2-way = free per m136), then stored as
// bf16x8 -> each wave store = 4 x 256 B contiguous segments (was 4 x 32 B).
// Requires M%256==0, N%128==0, K%64==0, grid%8==0.
// ---------------------------------------------------------------------------
#define CPAD 132

template <int RELU>
__global__ __launch_bounds__(512, 4) void gemm_bt2(const bf16* __restrict__ A,
                                                   const bf16* __restrict__ Bt,
                                                   const float* __restrict__ bias,
                                                   bf16* __restrict__ C,
                                                   int M, int N, int K, int nbx) {
    __shared__ __align__(16) bf16 smem[24576];  // 48 KB: As(32K) | Bs(16K)
    bf16* As = smem;
    bf16* Bs = smem + 16384;
    const int t = threadIdx.x;
    const int lane = t & 63;
    const int w = t >> 6;            // 0..7
    const int wm = w >> 1, wn = w & 1;

    const int nwg = gridDim.x;
    const int qch = nwg >> 3;
    const int swz = ((int)blockIdx.x & 7) * qch + ((int)blockIdx.x >> 3);
    const int bx = swz % nbx, by = swz / nbx;
    const long row0 = (long)by * 256;
    const long col0 = (long)bx * 128;

    const int srow = t >> 3;   // 0..63
    const int dslot = t & 7;
    const int gsl = dslot ^ (srow & 7);
    const bf16* Ag = A + (row0 + srow) * (long)K + gsl * 8;
    const bf16* Bg = Bt + (col0 + srow) * (long)K + gsl * 8;
    bf16* AsB = &As[w * 512];
    bf16* BsB = &Bs[w * 512];

    const int cm = lane & 15;
    const int kc = lane >> 4;

    f32x4 acc[4][4] = {};

    for (int k0 = 0; k0 < K; k0 += 64) {
#pragma unroll
        for (int q = 0; q < 4; ++q)
            gload_lds16(Ag + (long)q * 64 * K + k0, AsB + q * 4096);
#pragma unroll
        for (int q = 0; q < 2; ++q)
            gload_lds16(Bg + (long)q * 64 * K + k0, BsB + q * 4096);
        __syncthreads();
#pragma unroll
        for (int s = 0; s < 2; ++s) {
            bf16x8 af[4], bv[4];
#pragma unroll
            for (int i = 0; i < 4; ++i) {
                const int r = wm * 64 + i * 16 + cm;
                af[i] = *(const bf16x8*)&As[r * 64 + (((s * 4 + kc) ^ (r & 7)) * 8)];
            }
#pragma unroll
            for (int j = 0; j < 4; ++j) {
                const int r = wn * 64 + j * 16 + cm;
                bv[j] = *(const bf16x8*)&Bs[r * 64 + (((s * 4 + kc) ^ (r & 7)) * 8)];
            }
#pragma unroll
            for (int i = 0; i < 4; ++i)
#pragma unroll
                for (int j = 0; j < 4; ++j)
                    acc[i][j] = __builtin_amdgcn_mfma_f32_16x16x32_bf16(
                        af[i], bv[j], acc[i][j], 0, 0, 0);
        }
        __syncthreads();
    }

    // LDS-staged epilogue. K-loop's final barrier fences As/Bs reuse.
    const int r4 = kc * 4;
    const int rr = t >> 4;          // 0..31
    const int cc = (t & 15) * 8;    // 0..120
#pragma unroll
    for (int h = 0; h < 2; ++h) {
        if ((wm >> 1) == h) {
#pragma unroll
            for (int j = 0; j < 4; ++j) {
                const float bj = bias[col0 + wn * 64 + j * 16 + cm];
#pragma unroll
                for (int i = 0; i < 4; ++i) {
#pragma unroll
                    for (int r = 0; r < 4; ++r) {
                        const int rl = (wm & 1) * 64 + i * 16 + r4 + r;
                        float v = acc[i][j][r] + bj;
                        if (RELU) v = v > 0.0f ? v : 0.0f;
                        smem[rl * CPAD + wn * 64 + j * 16 + cm] = (bf16)v;
                    }
                }
            }
        }
        __syncthreads();
#pragma unroll
        for (int p = 0; p < 4; ++p) {
            const int rl = p * 32 + rr;
            *(bf16x8*)(C + (row0 + h * 128 + rl) * (long)N + col0 + cc) =
                *(const bf16x8*)&smem[rl * CPAD + cc];
        }
        __syncthreads();
    }
}

// ---------------------------------------------------------------------------
// Fused embedding gather + pairwise interaction + top_in assembly.
// ---------------------------------------------------------------------------
__global__ __launch_bounds__(256) void interact_k(const float* __restrict__ emb,
                                                  const int* __restrict__ cat,
                                                  const bf16* __restrict__ bottom,
                                                  bf16* __restrict__ top_in) {
    __shared__ float gram[4][32 * 32];
    __shared__ __align__(16) bf16 rowbuf[4][512];
    const int t = threadIdx.x;
    const int lane = t & 63;
    const int w = t >> 6;
    const long s = (long)blockIdx.x * 4 + w;

    const int rl = lane & 15;
    const int kg = lane >> 4;

    bf16x8 f[2][4];
#pragma unroll
    for (int i = 0; i < 2; ++i) {
        const int r = i * 16 + rl;
        const float* rowp = nullptr;
        if (r >= 1 && r <= 26) {
            const int idx = cat[s * T_CAT + (r - 1)];
            rowp = emb + ((long)(r - 1) * V_SZ + idx) * E_SZ;
        }
#pragma unroll
        for (int ks = 0; ks < 4; ++ks) {
            const int c = ks * 32 + kg * 8;
            bf16x8 v = {};
            if (r == 0) {
                v = *(const bf16x8*)(bottom + s * 128 + c);
            } else if (r <= 26) {
                const float4 v0 = *(const float4*)(rowp + c);
                const float4 v1 = *(const float4*)(rowp + c + 4);
                v[0]=(bf16)v0.x; v[1]=(bf16)v0.y; v[2]=(bf16)v0.z; v[3]=(bf16)v0.w;
                v[4]=(bf16)v1.x; v[5]=(bf16)v1.y; v[6]=(bf16)v1.z; v[7]=(bf16)v1.w;
            }
            f[i][ks] = v;
        }
    }

    f32x4 a00 = {}, a01 = {}, a11 = {};
#pragma unroll
    for (int ks = 0; ks < 4; ++ks) {
        a00 = __builtin_amdgcn_mfma_f32_16x16x32_bf16(f[0][ks], f[0][ks], a00, 0, 0, 0);
        a01 = __builtin_amdgcn_mfma_f32_16x16x32_bf16(f[0][ks], f[1][ks], a01, 0, 0, 0);
        a11 = __builtin_amdgcn_mfma_f32_16x16x32_bf16(f[1][ks], f[1][ks], a11, 0, 0, 0);
    }

    const int r4 = kg * 4;
#pragma unroll
    for (int r = 0; r < 4; ++r) {
        gram[w][(r4 + r) * 32 + rl]           = a00[r];
        gram[w][(r4 + r) * 32 + 16 + rl]      = a01[r];
        gram[w][(16 + r4 + r) * 32 + 16 + rl] = a11[r];
    }
    asm volatile("s_waitcnt lgkmcnt(0)" ::: "memory");
    __builtin_amdgcn_sched_barrier(0);

    if (lane < 16)
        ((bf16x8*)&rowbuf[w][0])[lane] = ((const bf16x8*)(bottom + s * 128))[lane];
#pragma unroll
    for (int q = 0; q < 6; ++q) {
        const int p = q * 64 + lane;
        if (p < 351) rowbuf[w][128 + p] = (bf16)gram[w][kTriu.v[p]];
    }
    if (lane >= 31) rowbuf[w][448 + lane] = (bf16)0.0f;
    asm volatile("s_waitcnt lgkmcnt(0)" ::: "memory");
    __builtin_amdgcn_sched_barrier(0);

    *(bf16x8*)(top_in + s * 512 + lane * 8) = *(const bf16x8*)&rowbuf[w][lane * 8];
}

// ---------------------------------------------------------------------------
extern "C" void kernel_launch(void* const* d_in, const int* in_sizes, int n_in,
                              void* d_out, int out_size, void* d_ws, size_t ws_size,
                              hipStream_t stream) {
    const float* numerical = (const float*)d_in[0];
    const int*   cat       = (const int*)d_in[1];
    const float* emb       = (const float*)d_in[2];
    const float* bw0 = (const float*)d_in[3];
    const float* bb0 = (const float*)d_in[4];
    const float* bw1 = (const float*)d_in[5];
    const float* bb1 = (const float*)d_in[6];
    const float* bw2 = (const float*)d_in[7];
    const float* bb2 = (const float*)d_in[8];
    const float* tw0 = (const float*)d_in[9];
    const float* tb0 = (const float*)d_in[10];
    const float* tw1 = (const float*)d_in[11];
    const float* tb1 = (const float*)d_in[12];
    const float* tw2 = (const float*)d_in[13];
    const float* tb2 = (const float*)d_in[14];
    const float* tw3 = (const float*)d_in[15];
    const float* tb3 = (const float*)d_in[16];
    const float* tw4 = (const float*)d_in[17];
    const float* tb4 = (const float*)d_in[18];
    float* out = (float*)d_out;

    char* ws = (char*)d_ws;
    size_t off = 0;
    auto alloc = [&](size_t bytes) {
        char* p = ws + off;
        off += (bytes + 255) & ~(size_t)255;
        return p;
    };
    bf16* wt0b = (bf16*)alloc((size_t)512 * 64 * 2);
    bf16* wt1b = (bf16*)alloc((size_t)256 * 512 * 2);
    bf16* wt2b = (bf16*)alloc((size_t)128 * 256 * 2);
    bf16* wt0t = (bf16*)alloc((size_t)1024 * 512 * 2);
    bf16* wt1t = (bf16*)alloc((size_t)1024 * 1024 * 2);
    bf16* wt2t = (bf16*)alloc((size_t)512 * 1024 * 2);
    bf16* wt3t = (bf16*)alloc((size_t)256 * 512 * 2);
    bf16* xpad = (bf16*)alloc((size_t)B_SZ * 64 * 2);
    bf16* h0   = (bf16*)alloc((size_t)B_SZ * 512 * 2);
    bf16* h1   = (bf16*)alloc((size_t)B_SZ * 256 * 2);
    bf16* bot  = (bf16*)alloc((size_t)B_SZ * 128 * 2);
    bf16* t0   = (bf16*)alloc((size_t)B_SZ * 1024 * 2);
    bf16* t1   = (bf16*)alloc((size_t)B_SZ * 1024 * 2);
    bf16* top_in = h0;
    bf16* t2 = t0;

    CJobs js;
    js.j[0] = {bw0, wt0b, 16, 512, 64, 0, 1};
    js.j[1] = {bw1, wt1b, 512, 256, 512, 8, 8};
    js.j[2] = {bw2, wt2b, 256, 128, 256, 40, 4};
    js.j[3] = {tw0, wt0t, 480, 1024, 512, 48, 8};
    js.j[4] = {tw1, wt1t, 1024, 1024, 1024, 176, 16};
    js.j[5] = {tw2, wt2t, 1024, 512, 1024, 432, 16};
    js.j[6] = {tw3, wt3t, 512, 256, 512, 560, 8};

    prep<<<PREP_BLKS, 256, 0, stream>>>(js, numerical, xpad, out, tb4);

    // bottom MLP
    gemm_bt<1><<<dim3(4, 256), 256, 0, stream>>>(xpad, wt0b, bb0, h0, B_SZ, 512, 64);
    gemm_bt<1><<<dim3(2, 256), 256, 0, stream>>>(h0, wt1b, bb1, h1, B_SZ, 256, 512);
    gemm_bt<1><<<dim3(1, 256), 256, 0, stream>>>(h1, wt2b, bb2, bot, B_SZ, 128, 256);

    interact_k<<<B_SZ / 4, 256, 0, stream>>>(emb, cat, bot, top_in);

    // top MLP: big 3 on gemm_bt2 (LDS-staged epilogue); final two layers fused
    gemm_bt2<1><<<dim3(1024), 512, 0, stream>>>(top_in, wt0t, tb0, t0, B_SZ, 1024, 512, 8);
    gemm_bt2<1><<<dim3(1024), 512, 0, stream>>>(t0, wt1t, tb1, t1, B_SZ, 1024, 1024, 8);
    gemm_bt2<1><<<dim3(512), 512, 0, stream>>>(t1, wt2t, tb2, t2, B_SZ, 512, 1024, 4);
    gemm_bt<1, 1><<<dim3(2, 256), 256, 0, stream>>>(t2, wt3t, tb3, nullptr,
                                                    B_SZ, 256, 512, tw4, out);
}